// Round 1
// baseline (615.478 us; speedup 1.0000x reference)
//
#include <hip/hip_runtime.h>
#include <cstdint>
#include <cstddef>

#define DEV __device__ __forceinline__

typedef __attribute__((ext_vector_type(8))) short bf16x8;
typedef __attribute__((ext_vector_type(4))) float f32x4;

typedef const __attribute__((address_space(1))) void gl_void;
typedef __attribute__((address_space(3))) void lds_void;

// ---------- small helpers ----------
DEV unsigned short f2bf(float f){
  union { float f; uint32_t u; } v; v.f = f;
  uint32_t r = v.u + 0x7FFFu + ((v.u >> 16) & 1u);  // RNE
  return (unsigned short)(r >> 16);
}
DEV float bf2f(unsigned short u){
  union { uint32_t u; float f; } v; v.u = ((uint32_t)u) << 16; return v.f;
}
DEV uint32_t packbf2(float a, float b){
  return (uint32_t)f2bf(a) | ((uint32_t)f2bf(b) << 16);
}

// ================= LayerNorm (fp32 in -> bf16 out, optional fp32 out) =================
__global__ void ln_kernel(const float* __restrict__ x, const float* __restrict__ gw,
                          const float* __restrict__ bw, unsigned short* __restrict__ obf,
                          float* __restrict__ of32)
{
  const int row = blockIdx.x, t = threadIdx.x;
  const float4 v = ((const float4*)(x + (size_t)row*1024))[t];
  float s  = v.x + v.y + v.z + v.w;
  float s2 = v.x*v.x + v.y*v.y + v.z*v.z + v.w*v.w;
  #pragma unroll
  for (int o = 32; o >= 1; o >>= 1){ s += __shfl_down(s, o); s2 += __shfl_down(s2, o); }
  __shared__ float red[8];
  const int w = t >> 6, ln = t & 63;
  if (ln == 0){ red[w] = s; red[4+w] = s2; }
  __syncthreads();
  const float fs  = red[0]+red[1]+red[2]+red[3];
  const float fs2 = red[4]+red[5]+red[6]+red[7];
  const float mean = fs * (1.0f/1024.0f);
  const float var  = fs2 * (1.0f/1024.0f) - mean*mean;
  const float rstd = rsqrtf(var + 1e-5f);
  const float4 gv = ((const float4*)gw)[t];
  const float4 bv = ((const float4*)bw)[t];
  float4 o4;
  o4.x = (v.x-mean)*rstd*gv.x + bv.x;
  o4.y = (v.y-mean)*rstd*gv.y + bv.y;
  o4.z = (v.z-mean)*rstd*gv.z + bv.z;
  o4.w = (v.w-mean)*rstd*gv.w + bv.w;
  if (of32) ((float4*)(of32 + (size_t)row*1024))[t] = o4;
  ushort4 ob; ob.x = f2bf(o4.x); ob.y = f2bf(o4.y); ob.z = f2bf(o4.z); ob.w = f2bf(o4.w);
  ((ushort4*)(obf + (size_t)row*1024))[t] = ob;
}

// ================= transpose + fp32->bf16  (out[C][R] = in[R][C]) =================
__global__ void transpose_cvt(const float* __restrict__ in, unsigned short* __restrict__ out,
                              int R, int C)
{
  __shared__ float tile[32][33];
  const int c0 = blockIdx.x*32, r0 = blockIdx.y*32;
  const int tx = threadIdx.x & 31, ty = threadIdx.x >> 5;   // 32 x 8
  #pragma unroll
  for (int i = 0; i < 32; i += 8)
    tile[ty+i][tx] = in[(size_t)(r0+ty+i)*C + c0 + tx];
  __syncthreads();
  #pragma unroll
  for (int i = 0; i < 32; i += 8)
    out[(size_t)(c0+ty+i)*R + r0 + tx] = f2bf(tile[tx][ty+i]);
}

// ================= fp32 -> bf16 cast (vectorized, exact grid) =================
__global__ void cvt_bf16x4(const float* __restrict__ in, unsigned short* __restrict__ out)
{
  const int i = blockIdx.x*256 + threadIdx.x;
  const float4 v = ((const float4*)in)[i];
  ushort4 o; o.x = f2bf(v.x); o.y = f2bf(v.y); o.z = f2bf(v.z); o.w = f2bf(v.w);
  ((ushort4*)out)[i] = o;
}

// ================= codebook squared norms (fp32) =================
__global__ void cbn2_kernel(const float* __restrict__ cb, float* __restrict__ cbn2)
{
  const int w = threadIdx.x >> 6, ln = threadIdx.x & 63;
  const int code = blockIdx.x*4 + w;           // 4096 codes total
  const float4* cr = (const float4*)(cb + (size_t)code*1024);
  float s = 0.f;
  for (int i = ln; i < 256; i += 64){ float4 v = cr[i]; s += v.x*v.x+v.y*v.y+v.z*v.z+v.w*v.w; }
  #pragma unroll
  for (int o = 32; o >= 1; o >>= 1) s += __shfl_down(s, o);
  if (ln == 0) cbn2[code] = s;
}

// ================= RoPE in-place on q,k (bf16) =================
__global__ void rope_kernel(unsigned short* __restrict__ q, unsigned short* __restrict__ k)
{
  const int tid = blockIdx.x*256 + threadIdx.x;        // 2*2048*16*32 = 2097152
  const int j  = tid & 31;
  const int hh = (tid >> 5) & 15;
  const int s_ = (tid >> 9) & 2047;
  const int b  = tid >> 20;
  const float inv = exp2f(-(float)j * 0.4152410118609203f);  // log2(10000)/32
  const float f = (float)s_ * inv;
  float sn, cs; sincosf(f, &sn, &cs);
  const size_t base = ((size_t)(b*2048 + s_))*1024 + hh*64 + j;
  {
    float x1 = bf2f(q[base]), x2 = bf2f(q[base+32]);
    q[base]    = f2bf(x1*cs - x2*sn);
    q[base+32] = f2bf(x2*cs + x1*sn);
  }
  {
    float x1 = bf2f(k[base]), x2 = bf2f(k[base+32]);
    k[base]    = f2bf(x1*cs - x2*sn);
    k[base+32] = f2bf(x2*cs + x1*sn);
  }
}

// ================= GEMM: C[M,N] = A[M,K] @ B (BT given as [N,K]), 128x128 tile =================
// EPI: 0 none, 1 silu, 2 gelu(exact). BIAS adds bias[col]. RES adds resid[row*N+col] (after EPI).
template<int EPI, bool BIAS, bool RES, bool OUTBF>
__global__ __launch_bounds__(256, 2) void gemm_bt(
    const unsigned short* __restrict__ A, const unsigned short* __restrict__ BT,
    void* __restrict__ Cv, const float* __restrict__ bias, const float* __restrict__ resid,
    int M, int N, int K)
{
  __shared__ __align__(16) unsigned short As[2][128*32];
  __shared__ __align__(16) unsigned short Bs[2][128*32];
  const int t = threadIdx.x;
  const int w = t >> 6, ln = t & 63, lg = ln >> 4, lc = ln & 15;
  const int m0 = blockIdx.y * 128, n0 = blockIdx.x * 128;
  const int wr = (w >> 1) * 64, wc = (w & 1) * 64;
  f32x4 acc[4][4] = {};
  const int nkt = K >> 5;

  auto stage = [&](int buf, int kt){
    #pragma unroll
    for (int c = 0; c < 2; ++c){
      const int chunk = c*256 + t;
      const int row = chunk >> 2, ke = (chunk & 3) * 8;
      __builtin_amdgcn_global_load_lds(
          (gl_void*)(A + (size_t)(m0+row)*K + (size_t)kt*32 + ke),
          (lds_void*)&As[buf][(c*256 + w*64)*8], 16, 0, 0);
      __builtin_amdgcn_global_load_lds(
          (gl_void*)(BT + (size_t)(n0+row)*K + (size_t)kt*32 + ke),
          (lds_void*)&Bs[buf][(c*256 + w*64)*8], 16, 0, 0);
    }
  };

  stage(0, 0);
  __syncthreads();
  for (int kt = 0; kt < nkt; ++kt){
    const int cur = kt & 1;
    if (kt + 1 < nkt) stage(cur ^ 1, kt + 1);
    bf16x8 af[4], bfr[4];
    #pragma unroll
    for (int i = 0; i < 4; ++i){
      af[i]  = *(const bf16x8*)&As[cur][(wr + i*16 + lc)*32 + lg*8];
      bfr[i] = *(const bf16x8*)&Bs[cur][(wc + i*16 + lc)*32 + lg*8];
    }
    #pragma unroll
    for (int m = 0; m < 4; ++m)
      #pragma unroll
      for (int n = 0; n < 4; ++n)
        acc[m][n] = __builtin_amdgcn_mfma_f32_16x16x32_bf16(af[m], bfr[n], acc[m][n], 0, 0, 0);
    __syncthreads();
  }

  #pragma unroll
  for (int m = 0; m < 4; ++m){
    #pragma unroll
    for (int n = 0; n < 4; ++n){
      #pragma unroll
      for (int r = 0; r < 4; ++r){
        const int row = m0 + wr + m*16 + lg*4 + r;
        const int col = n0 + wc + n*16 + lc;
        float v = acc[m][n][r];
        if constexpr (BIAS) v += bias[col];
        if constexpr (EPI == 1) v = v * (1.0f / (1.0f + __expf(-v)));
        if constexpr (EPI == 2) v = 0.5f * v * (1.0f + erff(v * 0.70710678118654752f));
        if constexpr (RES) v += resid[(size_t)row*N + col];
        if constexpr (OUTBF) ((unsigned short*)Cv)[(size_t)row*N + col] = f2bf(v);
        else                 ((float*)Cv)[(size_t)row*N + col] = v;
      }
    }
  }
}

// ================= Retention: per (b,h), 256-row q tiles, k-tile loop =================
// S^T = mfma(K, Q) so each lane holds 4 consecutive kp of one q-row -> decay+mask in-register,
// pack bf16 pairs, ds_write_b64 into per-wave P[q][kp]; PV = mfma(P, V^T-staged).
// Output fused with gate: og = O * g (g already silu'd), bf16.
__global__ __launch_bounds__(256, 1) void retention_kernel(
    const unsigned short* __restrict__ qb, const unsigned short* __restrict__ kb,
    const unsigned short* __restrict__ vb, const unsigned short* __restrict__ gb,
    unsigned short* __restrict__ og)
{
  __shared__ __align__(16) unsigned short Kt[64*72];
  __shared__ __align__(16) unsigned short Vt[64*72];
  __shared__ __align__(16) unsigned short Pw[4][64*72];

  const int t = threadIdx.x, w = t >> 6, ln = t & 63, lg = ln >> 4, lc = ln & 15;
  const int bh = blockIdx.x, qt = blockIdx.y;
  const int b = bh >> 4, hh = bh & 15;
  const int q0w = qt*256 + w*64;

  const float gamma = 1.0f - exp2f(-5.0f - (float)hh);
  const float lg2g  = log2f(gamma);
  float gpr[4];
  #pragma unroll
  for (int r = 0; r < 4; ++r) gpr[r] = exp2f(-lg2g * (float)r);   // gamma^{-r}

  // Q fragments (kept in registers): Qf[nt][ks]
  bf16x8 Qf[4][2];
  #pragma unroll
  for (int nt = 0; nt < 4; ++nt)
    #pragma unroll
    for (int ks = 0; ks < 2; ++ks){
      const uint4 v = *(const uint4*)(qb + ((size_t)(b*2048 + q0w + nt*16 + lc))*1024
                                      + hh*64 + ks*32 + lg*8);
      union { uint4 u; bf16x8 f; } cv; cv.u = v;
      Qf[nt][ks] = cv.f;
    }

  f32x4 accO[4][4] = {};
  const int ntiles = qt*4 + 4;

  for (int kt = 0; kt < ntiles; ++kt){
    // stage K (padded linear) and V (transposed) for this 64-kpos tile
    #pragma unroll
    for (int c = 0; c < 2; ++c){
      const int chunk = c*256 + t;
      const int row = chunk >> 3, d0 = (chunk & 7) * 8;
      const size_t gofs = ((size_t)(b*2048 + kt*64 + row))*1024 + hh*64 + d0;
      const uint4 kv = *(const uint4*)(kb + gofs);
      *(uint4*)&Kt[row*72 + d0] = kv;
      const uint4 vv = *(const uint4*)(vb + gofs);
      union { uint4 u; unsigned short s[8]; } uv; uv.u = vv;
      #pragma unroll
      for (int j = 0; j < 8; ++j) Vt[(d0+j)*72 + row] = uv.s[j];
    }
    __syncthreads();

    if (kt <= qt*4 + w){
      // S^T and P-write
      #pragma unroll
      for (int mt = 0; mt < 4; ++mt){
        f32x4 st[4] = {};
        #pragma unroll
        for (int ks = 0; ks < 2; ++ks){
          const bf16x8 Kf = *(const bf16x8*)&Kt[(mt*16 + lc)*72 + ks*32 + lg*8];
          #pragma unroll
          for (int nt = 0; nt < 4; ++nt)
            st[nt] = __builtin_amdgcn_mfma_f32_16x16x32_bf16(Kf, Qf[nt][ks], st[nt], 0, 0, 0);
        }
        const int kp0 = kt*64 + mt*16 + lg*4;
        #pragma unroll
        for (int nt = 0; nt < 4; ++nt){
          const int qa = qt*256 + w*64 + nt*16 + lc;
          const int delta0 = qa - kp0;
          const float dec0 = exp2f(lg2g * (float)delta0) * 0.125f;
          float vals[4];
          #pragma unroll
          for (int r = 0; r < 4; ++r)
            vals[r] = (delta0 >= r) ? st[nt][r] * dec0 * gpr[r] : 0.0f;
          uint2 pk; pk.x = packbf2(vals[0], vals[1]); pk.y = packbf2(vals[2], vals[3]);
          *(uint2*)&Pw[w][(nt*16 + lc)*72 + mt*16 + lg*4] = pk;
        }
      }
      // PV
      #pragma unroll
      for (int ks = 0; ks < 2; ++ks){
        bf16x8 Vf[4];
        #pragma unroll
        for (int n = 0; n < 4; ++n)
          Vf[n] = *(const bf16x8*)&Vt[(n*16 + lc)*72 + ks*32 + lg*8];
        #pragma unroll
        for (int ma = 0; ma < 4; ++ma){
          const bf16x8 Pf = *(const bf16x8*)&Pw[w][(ma*16 + lc)*72 + ks*32 + lg*8];
          #pragma unroll
          for (int n = 0; n < 4; ++n)
            accO[ma][n] = __builtin_amdgcn_mfma_f32_16x16x32_bf16(Pf, Vf[n], accO[ma][n], 0, 0, 0);
        }
      }
    }
    __syncthreads();
  }

  // epilogue: og = O * g
  #pragma unroll
  for (int ma = 0; ma < 4; ++ma){
    #pragma unroll
    for (int n = 0; n < 4; ++n){
      #pragma unroll
      for (int r = 0; r < 4; ++r){
        const int row = b*2048 + qt*256 + w*64 + ma*16 + lg*4 + r;
        const int col = hh*64 + n*16 + lc;
        const float gv = bf2f(gb[(size_t)row*1024 + col]);
        og[(size_t)row*1024 + col] = f2bf(accO[ma][n][r] * gv);
      }
    }
  }
}

// ================= RVQ argmin over 1024 codes (one wave per row) =================
__global__ void argmin_kernel(const float* __restrict__ scores, const float* __restrict__ cbn2_l,
                              int* __restrict__ idx)
{
  const int wv = threadIdx.x >> 6, ln = threadIdx.x & 63;
  const int row = blockIdx.x*4 + wv;
  const float* sr = scores + (size_t)row*1024;
  float best = 3.4e38f; int bi = 0;
  for (int c = ln; c < 1024; c += 64){
    const float d = cbn2_l[c] - 2.0f * sr[c];
    if (d < best){ best = d; bi = c; }
  }
  #pragma unroll
  for (int o = 32; o >= 1; o >>= 1){
    const float ob = __shfl_xor(best, o);
    const int oi = __shfl_xor(bi, o);
    if (ob < best || (ob == best && oi < bi)){ best = ob; bi = oi; }
  }
  if (ln == 0) idx[row] = bi;
}

// ================= RVQ residual/total update + per-row ql partial =================
__global__ void rvq_update(const float* __restrict__ cb_l, const int* __restrict__ idx,
                           float* __restrict__ res, unsigned short* __restrict__ resb,
                           float* __restrict__ total, float* __restrict__ qlpart, int lvl)
{
  const int m = blockIdx.x, t = threadIdx.x;
  const int id = idx[m];
  const float4 qv = ((const float4*)(cb_l + (size_t)id*1024))[t];
  const float4 rv = ((const float4*)(res + (size_t)m*1024))[t];
  float4 nr; nr.x = rv.x - qv.x; nr.y = rv.y - qv.y; nr.z = rv.z - qv.z; nr.w = rv.w - qv.w;
  float4 tv;
  if (lvl == 0){ tv = qv; }
  else { tv = ((const float4*)(total + (size_t)m*1024))[t];
         tv.x += qv.x; tv.y += qv.y; tv.z += qv.z; tv.w += qv.w; }
  ((float4*)(total + (size_t)m*1024))[t] = tv;
  ((float4*)(res   + (size_t)m*1024))[t] = nr;
  ushort4 nb; nb.x = f2bf(nr.x); nb.y = f2bf(nr.y); nb.z = f2bf(nr.z); nb.w = f2bf(nr.w);
  ((ushort4*)(resb + (size_t)m*1024))[t] = nb;
  float s = nr.x*nr.x + nr.y*nr.y + nr.z*nr.z + nr.w*nr.w;
  #pragma unroll
  for (int o = 32; o >= 1; o >>= 1) s += __shfl_down(s, o);
  __shared__ float red[4];
  if ((t & 63) == 0) red[t >> 6] = s;
  __syncthreads();
  if (t == 0) qlpart[lvl*4096 + m] = red[0]+red[1]+red[2]+red[3];
}

// ================= finals =================
__global__ void final_add(const float* __restrict__ x2, const float* __restrict__ total,
                          float* __restrict__ out)
{
  int i = blockIdx.x*256 + threadIdx.x;
  const float4* a = (const float4*)x2;
  const float4* b = (const float4*)total;
  float4* o = (float4*)out;
  for (; i < 4194304/4; i += gridDim.x*256){
    float4 va = a[i], vb = b[i];
    va.x += vb.x; va.y += vb.y; va.z += vb.z; va.w += vb.w;
    o[i] = va;
  }
}

__global__ void ql_final(const float* __restrict__ qlpart, float* __restrict__ outs)
{
  const int t = threadIdx.x;
  float s = 0.f;
  for (int i = t; i < 16384; i += 256) s += qlpart[i];
  #pragma unroll
  for (int o = 32; o >= 1; o >>= 1) s += __shfl_down(s, o);
  __shared__ float red[4];
  if ((t & 63) == 0) red[t >> 6] = s;
  __syncthreads();
  if (t == 0){
    const float q = (red[0]+red[1]+red[2]+red[3]) * (1.0f/4194304.0f) * 0.25f;
    outs[0] = q; outs[1] = q;
  }
}

// ================= launcher =================
extern "C" void kernel_launch(void* const* d_in, const int* in_sizes, int n_in,
                              void* d_out, int out_size, void* d_ws, size_t ws_size,
                              hipStream_t stream)
{
  const float* x     = (const float*)d_in[0];
  const float* ln1_g = (const float*)d_in[1];
  const float* ln1_b = (const float*)d_in[2];
  const float* wq    = (const float*)d_in[3];
  const float* wk    = (const float*)d_in[4];
  const float* wv    = (const float*)d_in[5];
  const float* wg    = (const float*)d_in[6];
  const float* wo    = (const float*)d_in[7];
  const float* ln2_g = (const float*)d_in[8];
  const float* ln2_b = (const float*)d_in[9];
  const float* w1    = (const float*)d_in[10];
  const float* b1    = (const float*)d_in[11];
  const float* w2    = (const float*)d_in[12];
  const float* b2    = (const float*)d_in[13];
  const float* ln3_g = (const float*)d_in[14];
  const float* ln3_b = (const float*)d_in[15];
  const float* cb    = (const float*)d_in[16];

  char* ws = (char*)d_ws;
  const size_t MB = 1024*1024;
  unsigned short* wqT  = (unsigned short*)(ws + 0*MB);
  unsigned short* wkT  = (unsigned short*)(ws + 2*MB);
  unsigned short* wvT  = (unsigned short*)(ws + 4*MB);
  unsigned short* wgT  = (unsigned short*)(ws + 6*MB);
  unsigned short* woT  = (unsigned short*)(ws + 8*MB);
  unsigned short* w1T  = (unsigned short*)(ws + 10*MB);
  unsigned short* w2T  = (unsigned short*)(ws + 18*MB);
  unsigned short* cbbf = (unsigned short*)(ws + 26*MB);
  float* cbn2   = (float*)(ws + 34*MB);
  float* qlpart = (float*)(ws + 34*MB + 16*1024);
  int*   idxb   = (int*)  (ws + 34*MB + 80*1024);
  unsigned short* hbf  = (unsigned short*)(ws + 35*MB);
  unsigned short* qbuf = (unsigned short*)(ws + 43*MB);
  unsigned short* kbuf = (unsigned short*)(ws + 51*MB);
  unsigned short* vbuf = (unsigned short*)(ws + 59*MB);
  unsigned short* gbuf = (unsigned short*)(ws + 67*MB);
  unsigned short* ogb  = (unsigned short*)(ws + 75*MB);
  float* x1     = (float*)(ws + 83*MB);
  unsigned short* h2   = (unsigned short*)(ws + 99*MB);
  unsigned short* a1   = (unsigned short*)(ws + 107*MB);
  float* x2     = (float*)(ws + 139*MB);
  float* resf   = (float*)(ws + 155*MB);
  unsigned short* resb = (unsigned short*)(ws + 171*MB);
  float* scores = (float*)(ws + 179*MB);

  float* outf = (float*)d_out;

  // --- weight prep ---
  hipLaunchKernelGGL(transpose_cvt, dim3(32,32),  dim3(256), 0, stream, wq, wqT, 1024, 1024);
  hipLaunchKernelGGL(transpose_cvt, dim3(32,32),  dim3(256), 0, stream, wk, wkT, 1024, 1024);
  hipLaunchKernelGGL(transpose_cvt, dim3(32,32),  dim3(256), 0, stream, wv, wvT, 1024, 1024);
  hipLaunchKernelGGL(transpose_cvt, dim3(32,32),  dim3(256), 0, stream, wg, wgT, 1024, 1024);
  hipLaunchKernelGGL(transpose_cvt, dim3(32,32),  dim3(256), 0, stream, wo, woT, 1024, 1024);
  hipLaunchKernelGGL(transpose_cvt, dim3(128,32), dim3(256), 0, stream, w1, w1T, 1024, 4096);
  hipLaunchKernelGGL(transpose_cvt, dim3(32,128), dim3(256), 0, stream, w2, w2T, 4096, 1024);
  hipLaunchKernelGGL(cvt_bf16x4,    dim3(4096),   dim3(256), 0, stream, cb, cbbf);
  hipLaunchKernelGGL(cbn2_kernel,   dim3(1024),   dim3(256), 0, stream, cb, cbn2);

  // --- retention sub-block ---
  hipLaunchKernelGGL(ln_kernel, dim3(4096), dim3(256), 0, stream, x, ln1_g, ln1_b, hbf, (float*)nullptr);
  hipLaunchKernelGGL((gemm_bt<0,false,false,true>), dim3(8,32), dim3(256), 0, stream,
                     hbf, wqT, (void*)qbuf, (const float*)nullptr, (const float*)nullptr, 4096, 1024, 1024);
  hipLaunchKernelGGL((gemm_bt<0,false,false,true>), dim3(8,32), dim3(256), 0, stream,
                     hbf, wkT, (void*)kbuf, (const float*)nullptr, (const float*)nullptr, 4096, 1024, 1024);
  hipLaunchKernelGGL((gemm_bt<0,false,false,true>), dim3(8,32), dim3(256), 0, stream,
                     hbf, wvT, (void*)vbuf, (const float*)nullptr, (const float*)nullptr, 4096, 1024, 1024);
  hipLaunchKernelGGL((gemm_bt<1,false,false,true>), dim3(8,32), dim3(256), 0, stream,
                     hbf, wgT, (void*)gbuf, (const float*)nullptr, (const float*)nullptr, 4096, 1024, 1024);
  hipLaunchKernelGGL(rope_kernel, dim3(8192), dim3(256), 0, stream, qbuf, kbuf);
  hipLaunchKernelGGL(retention_kernel, dim3(32,8), dim3(256), 0, stream, qbuf, kbuf, vbuf, gbuf, ogb);
  hipLaunchKernelGGL((gemm_bt<0,false,true,false>), dim3(8,32), dim3(256), 0, stream,
                     ogb, woT, (void*)x1, (const float*)nullptr, x, 4096, 1024, 1024);

  // --- MLP sub-block ---
  hipLaunchKernelGGL(ln_kernel, dim3(4096), dim3(256), 0, stream, x1, ln2_g, ln2_b, h2, (float*)nullptr);
  hipLaunchKernelGGL((gemm_bt<2,true,false,true>), dim3(32,32), dim3(256), 0, stream,
                     h2, w1T, (void*)a1, b1, (const float*)nullptr, 4096, 4096, 1024);
  hipLaunchKernelGGL((gemm_bt<0,true,true,false>), dim3(8,32), dim3(256), 0, stream,
                     a1, w2T, (void*)x2, b2, x1, 4096, 1024, 4096);

  // --- RVQ ---
  hipLaunchKernelGGL(ln_kernel, dim3(4096), dim3(256), 0, stream, x2, ln3_g, ln3_b, resb, resf);
  for (int lvl = 0; lvl < 4; ++lvl){
    hipLaunchKernelGGL((gemm_bt<0,false,false,false>), dim3(8,32), dim3(256), 0, stream,
                       resb, cbbf + (size_t)lvl*1024*1024, (void*)scores,
                       (const float*)nullptr, (const float*)nullptr, 4096, 1024, 1024);
    hipLaunchKernelGGL(argmin_kernel, dim3(1024), dim3(256), 0, stream,
                       scores, cbn2 + lvl*1024, idxb);
    hipLaunchKernelGGL(rvq_update, dim3(4096), dim3(256), 0, stream,
                       cb + (size_t)lvl*1024*1024, idxb, resf, resb,
                       (float*)(ws + 187*MB), qlpart, lvl);
  }

  // --- outputs ---
  hipLaunchKernelGGL(final_add, dim3(2048), dim3(256), 0, stream, x2, (float*)(ws + 187*MB), outf);
  hipLaunchKernelGGL(ql_final, dim3(1), dim3(256), 0, stream, qlpart, outf + 4194304);
}

// Round 2
// 511.345 us; speedup vs baseline: 1.2036x; 1.2036x over previous
//
#include <hip/hip_runtime.h>
#include <cstdint>
#include <cstddef>

#define DEV __device__ __forceinline__

typedef __attribute__((ext_vector_type(8))) short bf16x8;
typedef __attribute__((ext_vector_type(4))) float f32x4;

typedef const __attribute__((address_space(1))) void gl_void;
typedef __attribute__((address_space(3))) void lds_void;

// ---------- small helpers ----------
DEV unsigned short f2bf(float f){
  union { float f; uint32_t u; } v; v.f = f;
  uint32_t r = v.u + 0x7FFFu + ((v.u >> 16) & 1u);  // RNE
  return (unsigned short)(r >> 16);
}
DEV float bf2f(unsigned short u){
  union { uint32_t u; float f; } v; v.u = ((uint32_t)u) << 16; return v.f;
}
DEV uint32_t packbf2(float a, float b){
  return (uint32_t)f2bf(a) | ((uint32_t)f2bf(b) << 16);
}

// ================= LayerNorm (fp32 in -> bf16 out, optional fp32 out) =================
__global__ void ln_kernel(const float* __restrict__ x, const float* __restrict__ gw,
                          const float* __restrict__ bw, unsigned short* __restrict__ obf,
                          float* __restrict__ of32)
{
  const int row = blockIdx.x, t = threadIdx.x;
  const float4 v = ((const float4*)(x + (size_t)row*1024))[t];
  float s  = v.x + v.y + v.z + v.w;
  float s2 = v.x*v.x + v.y*v.y + v.z*v.z + v.w*v.w;
  #pragma unroll
  for (int o = 32; o >= 1; o >>= 1){ s += __shfl_down(s, o); s2 += __shfl_down(s2, o); }
  __shared__ float red[8];
  const int w = t >> 6, ln = t & 63;
  if (ln == 0){ red[w] = s; red[4+w] = s2; }
  __syncthreads();
  const float fs  = red[0]+red[1]+red[2]+red[3];
  const float fs2 = red[4]+red[5]+red[6]+red[7];
  const float mean = fs * (1.0f/1024.0f);
  const float var  = fs2 * (1.0f/1024.0f) - mean*mean;
  const float rstd = rsqrtf(var + 1e-5f);
  const float4 gv = ((const float4*)gw)[t];
  const float4 bv = ((const float4*)bw)[t];
  float4 o4;
  o4.x = (v.x-mean)*rstd*gv.x + bv.x;
  o4.y = (v.y-mean)*rstd*gv.y + bv.y;
  o4.z = (v.z-mean)*rstd*gv.z + bv.z;
  o4.w = (v.w-mean)*rstd*gv.w + bv.w;
  if (of32) ((float4*)(of32 + (size_t)row*1024))[t] = o4;
  ushort4 ob; ob.x = f2bf(o4.x); ob.y = f2bf(o4.y); ob.z = f2bf(o4.z); ob.w = f2bf(o4.w);
  ((ushort4*)(obf + (size_t)row*1024))[t] = ob;
}

// ================= transpose + fp32->bf16  (out[C][R] = in[R][C]) =================
__global__ void transpose_cvt(const float* __restrict__ in, unsigned short* __restrict__ out,
                              int R, int C)
{
  __shared__ float tile[32][33];
  const int c0 = blockIdx.x*32, r0 = blockIdx.y*32;
  const int tx = threadIdx.x & 31, ty = threadIdx.x >> 5;   // 32 x 8
  #pragma unroll
  for (int i = 0; i < 32; i += 8)
    tile[ty+i][tx] = in[(size_t)(r0+ty+i)*C + c0 + tx];
  __syncthreads();
  #pragma unroll
  for (int i = 0; i < 32; i += 8)
    out[(size_t)(c0+ty+i)*R + r0 + tx] = f2bf(tile[tx][ty+i]);
}

// ================= fp32 -> bf16 cast (vectorized, exact grid) =================
__global__ void cvt_bf16x4(const float* __restrict__ in, unsigned short* __restrict__ out)
{
  const int i = blockIdx.x*256 + threadIdx.x;
  const float4 v = ((const float4*)in)[i];
  ushort4 o; o.x = f2bf(v.x); o.y = f2bf(v.y); o.z = f2bf(v.z); o.w = f2bf(v.w);
  ((ushort4*)out)[i] = o;
}

// ================= codebook squared norms (fp32) =================
__global__ void cbn2_kernel(const float* __restrict__ cb, float* __restrict__ cbn2)
{
  const int w = threadIdx.x >> 6, ln = threadIdx.x & 63;
  const int code = blockIdx.x*4 + w;           // 4096 codes total
  const float4* cr = (const float4*)(cb + (size_t)code*1024);
  float s = 0.f;
  for (int i = ln; i < 256; i += 64){ float4 v = cr[i]; s += v.x*v.x+v.y*v.y+v.z*v.z+v.w*v.w; }
  #pragma unroll
  for (int o = 32; o >= 1; o >>= 1) s += __shfl_down(s, o);
  if (ln == 0) cbn2[code] = s;
}

// ================= RoPE in-place on q,k (bf16) =================
__global__ void rope_kernel(unsigned short* __restrict__ q, unsigned short* __restrict__ k)
{
  const int tid = blockIdx.x*256 + threadIdx.x;        // 2*2048*16*32 = 2097152
  const int j  = tid & 31;
  const int hh = (tid >> 5) & 15;
  const int s_ = (tid >> 9) & 2047;
  const int b  = tid >> 20;
  const float inv = exp2f(-(float)j * 0.4152410118609203f);  // log2(10000)/32
  const float f = (float)s_ * inv;
  float sn, cs; sincosf(f, &sn, &cs);
  const size_t base = ((size_t)(b*2048 + s_))*1024 + hh*64 + j;
  {
    float x1 = bf2f(q[base]), x2 = bf2f(q[base+32]);
    q[base]    = f2bf(x1*cs - x2*sn);
    q[base+32] = f2bf(x2*cs + x1*sn);
  }
  {
    float x1 = bf2f(k[base]), x2 = bf2f(k[base+32]);
    k[base]    = f2bf(x1*cs - x2*sn);
    k[base+32] = f2bf(x2*cs + x1*sn);
  }
}

// ================= GEMM: C[M,N] = A[M,K] @ B (BT given as [N,K]), 128x128 tile =================
// EPI: 0 none, 1 silu, 2 gelu(exact), 3 QKVG-split (silu on sect 3), 4 argmin-partials.
template<int EPI, bool BIAS, bool RES, bool OUTBF>
__global__ __launch_bounds__(256, 2) void gemm_bt(
    const unsigned short* __restrict__ A, const unsigned short* __restrict__ BT,
    void* __restrict__ Cv, const float* __restrict__ bias, const float* __restrict__ resid,
    int M, int N, int K)
{
  __shared__ __align__(16) unsigned short As[2][128*32];
  __shared__ __align__(16) unsigned short Bs[2][128*32];
  const int t = threadIdx.x;
  const int w = t >> 6, ln = t & 63, lg = ln >> 4, lc = ln & 15;
  const int m0 = blockIdx.y * 128, n0 = blockIdx.x * 128;
  const int wr = (w >> 1) * 64, wc = (w & 1) * 64;
  f32x4 acc[4][4] = {};
  const int nkt = K >> 5;

  auto stage = [&](int buf, int kt){
    #pragma unroll
    for (int c = 0; c < 2; ++c){
      const int chunk = c*256 + t;
      const int row = chunk >> 2, ke = (chunk & 3) * 8;
      __builtin_amdgcn_global_load_lds(
          (gl_void*)(A + (size_t)(m0+row)*K + (size_t)kt*32 + ke),
          (lds_void*)&As[buf][(c*256 + w*64)*8], 16, 0, 0);
      __builtin_amdgcn_global_load_lds(
          (gl_void*)(BT + (size_t)(n0+row)*K + (size_t)kt*32 + ke),
          (lds_void*)&Bs[buf][(c*256 + w*64)*8], 16, 0, 0);
    }
  };

  stage(0, 0);
  __syncthreads();
  for (int kt = 0; kt < nkt; ++kt){
    const int cur = kt & 1;
    if (kt + 1 < nkt) stage(cur ^ 1, kt + 1);
    bf16x8 af[4], bfr[4];
    #pragma unroll
    for (int i = 0; i < 4; ++i){
      af[i]  = *(const bf16x8*)&As[cur][(wr + i*16 + lc)*32 + lg*8];
      bfr[i] = *(const bf16x8*)&Bs[cur][(wc + i*16 + lc)*32 + lg*8];
    }
    #pragma unroll
    for (int m = 0; m < 4; ++m)
      #pragma unroll
      for (int n = 0; n < 4; ++n)
        acc[m][n] = __builtin_amdgcn_mfma_f32_16x16x32_bf16(af[m], bfr[n], acc[m][n], 0, 0, 0);
    __syncthreads();
  }

  if constexpr (EPI == 4){
    // per-row partial argmin of (cbn2[col] - 2*score) over this block's 128 cols
    #pragma unroll
    for (int m = 0; m < 4; ++m){
      #pragma unroll
      for (int r = 0; r < 4; ++r){
        float best = 3.4e38f; int bi = 0;
        #pragma unroll
        for (int n = 0; n < 4; ++n){
          const int col = n0 + wc + n*16 + lc;
          const float d = bias[col] - 2.0f*acc[m][n][r];
          if (d < best){ best = d; bi = col; }
        }
        #pragma unroll
        for (int o = 1; o < 16; o <<= 1){
          const float ob = __shfl_xor(best, o);
          const int oi = __shfl_xor(bi, o);
          if (ob < best || (ob == best && oi < bi)){ best = ob; bi = oi; }
        }
        if (lc == 0){
          const int row = m0 + wr + m*16 + lg*4 + r;
          ((float2*)Cv)[row*16 + blockIdx.x*2 + (w & 1)] = make_float2(best, (float)bi);
        }
      }
    }
    return;
  }

  #pragma unroll
  for (int m = 0; m < 4; ++m){
    #pragma unroll
    for (int n = 0; n < 4; ++n){
      #pragma unroll
      for (int r = 0; r < 4; ++r){
        const int row = m0 + wr + m*16 + lg*4 + r;
        const int col = n0 + wc + n*16 + lc;
        float v = acc[m][n][r];
        if constexpr (BIAS) v += bias[col];
        if constexpr (EPI == 1) v = v * (1.0f / (1.0f + __expf(-v)));
        if constexpr (EPI == 2) v = 0.5f * v * (1.0f + erff(v * 0.70710678118654752f));
        if constexpr (EPI == 3){
          const int sect = col >> 10;
          float ov = v;
          if (sect == 3) ov = v * (1.0f / (1.0f + __expf(-v)));
          ((unsigned short*)Cv)[(size_t)sect*4194304 + (size_t)row*1024 + (col & 1023)] = f2bf(ov);
          continue;
        }
        if constexpr (RES) v += resid[(size_t)row*N + col];
        if constexpr (OUTBF) ((unsigned short*)Cv)[(size_t)row*N + col] = f2bf(v);
        else                 ((float*)Cv)[(size_t)row*N + col] = v;
      }
    }
  }
}

// ================= Chunkwise retention, C=64 =================
// Phase 1: T_c[d][dv] = sum_i gamma^(64-i) k_i[d] v_i[dv]   (fp32 out)
__global__ __launch_bounds__(256, 2) void chunk_sum(
    const unsigned short* __restrict__ kb, const unsigned short* __restrict__ vb,
    float* __restrict__ Tbuf)
{
  __shared__ unsigned short KT[64*72];
  __shared__ unsigned short VT[64*72];
  const int t = threadIdx.x, w = t >> 6, ln = t & 63, lg = ln >> 4, lc = ln & 15;
  const int blk = blockIdx.x;          // bh*32 + c
  const int bh = blk >> 5, c = blk & 31;
  const int b = bh >> 4, hh = bh & 15;
  const float lg2g = log2f(1.0f - exp2f(-5.0f - (float)hh));
  #pragma unroll
  for (int ch = 0; ch < 2; ++ch){
    const int chunk = ch*256 + t;
    const int i = chunk >> 3, d0 = (chunk & 7)*8;
    const size_t gofs = ((size_t)(b*2048 + c*64 + i))*1024 + hh*64 + d0;
    const float wi = exp2f(lg2g * (float)(64 - i));
    union {uint4 u; unsigned short s[8];} kv, vv;
    kv.u = *(const uint4*)(kb + gofs);
    vv.u = *(const uint4*)(vb + gofs);
    #pragma unroll
    for (int j = 0; j < 8; ++j){
      KT[(d0+j)*72 + i] = f2bf(bf2f(kv.s[j]) * wi);
      VT[(d0+j)*72 + i] = vv.s[j];
    }
  }
  __syncthreads();
  f32x4 acc[4] = {};
  #pragma unroll
  for (int ks = 0; ks < 2; ++ks){
    const bf16x8 af = *(const bf16x8*)&KT[(w*16 + lc)*72 + ks*32 + lg*8];
    #pragma unroll
    for (int n = 0; n < 4; ++n){
      const bf16x8 bf = *(const bf16x8*)&VT[(n*16 + lc)*72 + ks*32 + lg*8];
      acc[n] = __builtin_amdgcn_mfma_f32_16x16x32_bf16(af, bf, acc[n], 0, 0, 0);
    }
  }
  float* out = Tbuf + (size_t)blk*4096;
  #pragma unroll
  for (int n = 0; n < 4; ++n)
    #pragma unroll
    for (int r = 0; r < 4; ++r)
      out[(w*16 + lg*4 + r)*64 + n*16 + lc] = acc[n][r];
}

// Phase 2: scan S_c = gamma^64 * S_{c-1} + T_{c-1};  statesT[bh][c][dv][d] (bf16)
__global__ void chunk_scan(const float* __restrict__ Tbuf, unsigned short* __restrict__ statesT)
{
  const int bh = blockIdx.x, t = threadIdx.x;
  const int hh = bh & 15;
  const float gamma = 1.0f - exp2f(-5.0f - (float)hh);
  const float g64 = exp2f(log2f(gamma) * 64.0f);
  float S[16];
  #pragma unroll
  for (int j = 0; j < 16; ++j) S[j] = 0.f;
  const int dv = t >> 2, d0 = (t & 3) * 16;
  for (int c = 0; c < 32; ++c){
    const size_t base = ((size_t)(bh*32 + c))*4096;
    // write state for chunk c (before adding T_c), layout [dv][d], coalesced
    union { unsigned short s[8]; uint4 u; } p0, p1;
    #pragma unroll
    for (int j = 0; j < 8; ++j){ p0.s[j] = f2bf(S[j]); p1.s[j] = f2bf(S[8+j]); }
    *(uint4*)(statesT + base + t*16)     = p0.u;
    *(uint4*)(statesT + base + t*16 + 8) = p1.u;
    #pragma unroll
    for (int j = 0; j < 16; ++j)
      S[j] = g64*S[j] + Tbuf[base + (size_t)(d0 + j)*64 + dv];
  }
}

// Phase 3: per chunk: O = decay.(QK^T/8) V + diag(gamma^i) (Q S_c)/8 ; og = O*g
__global__ __launch_bounds__(256, 2) void retention_chunk(
    const unsigned short* __restrict__ qb, const unsigned short* __restrict__ kb,
    const unsigned short* __restrict__ vb, const unsigned short* __restrict__ gb,
    const unsigned short* __restrict__ statesT, unsigned short* __restrict__ og)
{
  __shared__ unsigned short VT[64*72];
  __shared__ unsigned short Pw[64*72];
  const int t = threadIdx.x, w = t >> 6, ln = t & 63, lg = ln >> 4, lc = ln & 15;
  const int blk = blockIdx.x;          // bh*32 + c
  const int bh = blk >> 5, c = blk & 31;
  const int b = bh >> 4, hh = bh & 15;
  const float lg2g = log2f(1.0f - exp2f(-5.0f - (float)hh));
  float gpr[4];
  #pragma unroll
  for (int r = 0; r < 4; ++r) gpr[r] = exp2f(-lg2g * (float)r);   // gamma^{-r}
  const size_t rowbase = (size_t)(b*2048 + c*64);

  // stage V transposed: VT[dv][i]
  #pragma unroll
  for (int ch = 0; ch < 2; ++ch){
    const int chunk = ch*256 + t;
    const int i = chunk >> 3, d0 = (chunk & 7)*8;
    union {uint4 u; unsigned short s[8];} vv;
    vv.u = *(const uint4*)(vb + (rowbase + i)*1024 + hh*64 + d0);
    #pragma unroll
    for (int j = 0; j < 8; ++j) VT[(d0+j)*72 + i] = vv.s[j];
  }

  // Q frag (wave's 16 q-rows), K frags (all 64 k-rows) straight from global
  bf16x8 Qf[2], Kf[4][2];
  #pragma unroll
  for (int ks = 0; ks < 2; ++ks){
    union {uint4 u; bf16x8 f;} cv;
    cv.u = *(const uint4*)(qb + (rowbase + w*16 + lc)*1024 + hh*64 + ks*32 + lg*8);
    Qf[ks] = cv.f;
    #pragma unroll
    for (int mt = 0; mt < 4; ++mt){
      union {uint4 u; bf16x8 f;} kv;
      kv.u = *(const uint4*)(kb + (rowbase + mt*16 + lc)*1024 + hh*64 + ks*32 + lg*8);
      Kf[mt][ks] = kv.f;
    }
  }

  // S^T = K Q^T (C[kp][q]); each wave: 4 kp-tiles x its 16-q slice
  f32x4 st[4] = {};
  #pragma unroll
  for (int ks = 0; ks < 2; ++ks)
    #pragma unroll
    for (int mt = 0; mt < 4; ++mt)
      st[mt] = __builtin_amdgcn_mfma_f32_16x16x32_bf16(Kf[mt][ks], Qf[ks], st[mt], 0, 0, 0);

  __syncthreads();   // VT staged (Pw is per-wave-private rows)

  // decay+mask, pack to bf16, write P^T rows [q][kp]
  #pragma unroll
  for (int mt = 0; mt < 4; ++mt){
    const int kp = mt*16 + lg*4;
    const int qrow = w*16 + lc;
    const int delta0 = qrow - kp;
    const float dec0 = exp2f(lg2g * (float)delta0) * 0.125f;
    float vals[4];
    #pragma unroll
    for (int r = 0; r < 4; ++r)
      vals[r] = (delta0 >= r) ? st[mt][r] * dec0 * gpr[r] : 0.0f;
    uint2 pk; pk.x = packbf2(vals[0], vals[1]); pk.y = packbf2(vals[2], vals[3]);
    *(uint2*)&Pw[qrow*72 + kp] = pk;
  }

  // cross-chunk: acc = (Q @ S_c), then scale by gamma^i / 8
  f32x4 acc[4] = {};
  const unsigned short* Sbase = statesT + (size_t)blk*4096;
  #pragma unroll
  for (int ks = 0; ks < 2; ++ks)
    #pragma unroll
    for (int n = 0; n < 4; ++n){
      union {uint4 u; bf16x8 f;} sv;
      sv.u = *(const uint4*)(Sbase + (n*16 + lc)*64 + ks*32 + lg*8);
      acc[n] = __builtin_amdgcn_mfma_f32_16x16x32_bf16(Qf[ks], sv.f, acc[n], 0, 0, 0);
    }
  #pragma unroll
  for (int n = 0; n < 4; ++n)
    #pragma unroll
    for (int r = 0; r < 4; ++r)
      acc[n][r] *= exp2f(lg2g * (float)(w*16 + lg*4 + r)) * 0.125f;

  // intra-chunk: acc += P V
  #pragma unroll
  for (int ks = 0; ks < 2; ++ks){
    const bf16x8 Pf = *(const bf16x8*)&Pw[(w*16 + lc)*72 + ks*32 + lg*8];
    #pragma unroll
    for (int n = 0; n < 4; ++n){
      const bf16x8 Vf = *(const bf16x8*)&VT[(n*16 + lc)*72 + ks*32 + lg*8];
      acc[n] = __builtin_amdgcn_mfma_f32_16x16x32_bf16(Pf, Vf, acc[n], 0, 0, 0);
    }
  }

  // epilogue: og = O * g
  #pragma unroll
  for (int n = 0; n < 4; ++n){
    #pragma unroll
    for (int r = 0; r < 4; ++r){
      const size_t row = rowbase + w*16 + lg*4 + r;
      const int col = hh*64 + n*16 + lc;
      const float gv = bf2f(gb[row*1024 + col]);
      og[row*1024 + col] = f2bf(acc[n][r] * gv);
    }
  }
}

// ================= RVQ: argmin-from-partials + residual/total update =================
__global__ void rvq_update2(const float* __restrict__ cb_l, const float2* __restrict__ partials,
                            float* __restrict__ res, unsigned short* __restrict__ resb,
                            float* __restrict__ total, float* __restrict__ qlpart, int lvl)
{
  const int m = blockIdx.x, t = threadIdx.x;
  __shared__ int sid;
  if (t == 0){
    float best = 3.4e38f; int bi = 0;
    #pragma unroll
    for (int p = 0; p < 16; ++p){
      const float2 pr = partials[m*16 + p];
      if (pr.x < best){ best = pr.x; bi = (int)pr.y; }
    }
    sid = bi;
  }
  __syncthreads();
  const int id = sid;
  const float4 qv = ((const float4*)(cb_l + (size_t)id*1024))[t];
  const float4 rv = ((const float4*)(res + (size_t)m*1024))[t];
  float4 nr; nr.x = rv.x - qv.x; nr.y = rv.y - qv.y; nr.z = rv.z - qv.z; nr.w = rv.w - qv.w;
  float4 tv;
  if (lvl == 0){ tv = qv; }
  else { tv = ((const float4*)(total + (size_t)m*1024))[t];
         tv.x += qv.x; tv.y += qv.y; tv.z += qv.z; tv.w += qv.w; }
  ((float4*)(total + (size_t)m*1024))[t] = tv;
  ((float4*)(res   + (size_t)m*1024))[t] = nr;
  ushort4 nb; nb.x = f2bf(nr.x); nb.y = f2bf(nr.y); nb.z = f2bf(nr.z); nb.w = f2bf(nr.w);
  ((ushort4*)(resb + (size_t)m*1024))[t] = nb;
  float s = nr.x*nr.x + nr.y*nr.y + nr.z*nr.z + nr.w*nr.w;
  #pragma unroll
  for (int o = 32; o >= 1; o >>= 1) s += __shfl_down(s, o);
  __shared__ float red[4];
  if ((t & 63) == 0) red[t >> 6] = s;
  __syncthreads();
  if (t == 0) qlpart[lvl*4096 + m] = red[0]+red[1]+red[2]+red[3];
}

// ================= finals =================
__global__ void final_add(const float* __restrict__ x2, const float* __restrict__ total,
                          float* __restrict__ out)
{
  int i = blockIdx.x*256 + threadIdx.x;
  const float4* a = (const float4*)x2;
  const float4* b = (const float4*)total;
  float4* o = (float4*)out;
  for (; i < 4194304/4; i += gridDim.x*256){
    float4 va = a[i], vb = b[i];
    va.x += vb.x; va.y += vb.y; va.z += vb.z; va.w += vb.w;
    o[i] = va;
  }
}

__global__ void ql_final(const float* __restrict__ qlpart, float* __restrict__ outs)
{
  const int t = threadIdx.x;
  float s = 0.f;
  for (int i = t; i < 16384; i += 256) s += qlpart[i];
  #pragma unroll
  for (int o = 32; o >= 1; o >>= 1) s += __shfl_down(s, o);
  __shared__ float red[4];
  if ((t & 63) == 0) red[t >> 6] = s;
  __syncthreads();
  if (t == 0){
    const float q = (red[0]+red[1]+red[2]+red[3]) * (1.0f/4194304.0f) * 0.25f;
    outs[0] = q; outs[1] = q;
  }
}

// ================= launcher =================
extern "C" void kernel_launch(void* const* d_in, const int* in_sizes, int n_in,
                              void* d_out, int out_size, void* d_ws, size_t ws_size,
                              hipStream_t stream)
{
  const float* x     = (const float*)d_in[0];
  const float* ln1_g = (const float*)d_in[1];
  const float* ln1_b = (const float*)d_in[2];
  const float* wq    = (const float*)d_in[3];
  const float* wk    = (const float*)d_in[4];
  const float* wv    = (const float*)d_in[5];
  const float* wg    = (const float*)d_in[6];
  const float* wo    = (const float*)d_in[7];
  const float* ln2_g = (const float*)d_in[8];
  const float* ln2_b = (const float*)d_in[9];
  const float* w1    = (const float*)d_in[10];
  const float* b1    = (const float*)d_in[11];
  const float* w2    = (const float*)d_in[12];
  const float* b2    = (const float*)d_in[13];
  const float* ln3_g = (const float*)d_in[14];
  const float* ln3_b = (const float*)d_in[15];
  const float* cb    = (const float*)d_in[16];

  char* ws = (char*)d_ws;
  const size_t MB = 1024*1024;
  unsigned short* wqkvgT = (unsigned short*)(ws + 0*MB);   // wq^T,wk^T,wv^T,wg^T contiguous [4096][1024]
  unsigned short* woT  = (unsigned short*)(ws + 8*MB);
  unsigned short* w1T  = (unsigned short*)(ws + 10*MB);
  unsigned short* w2T  = (unsigned short*)(ws + 18*MB);
  unsigned short* cbbf = (unsigned short*)(ws + 26*MB);
  float* cbn2     = (float*)(ws + 34*MB);                  // 16KB
  float* qlpart   = (float*)(ws + 34*MB + 16*1024);        // 64KB
  float2* partials= (float2*)(ws + 34*MB + 128*1024);      // 512KB
  unsigned short* hbf  = (unsigned short*)(ws + 35*MB);
  unsigned short* qbuf = (unsigned short*)(ws + 43*MB);    // q,k,v,g contiguous (QKVG epilogue)
  unsigned short* kbuf = (unsigned short*)(ws + 51*MB);
  unsigned short* vbuf = (unsigned short*)(ws + 59*MB);
  unsigned short* gbuf = (unsigned short*)(ws + 67*MB);
  unsigned short* ogb  = (unsigned short*)(ws + 75*MB);
  float* x1     = (float*)(ws + 83*MB);
  unsigned short* h2   = (unsigned short*)(ws + 99*MB);
  unsigned short* a1   = (unsigned short*)(ws + 107*MB);
  float* x2     = (float*)(ws + 139*MB);
  float* Tbuf   = (float*)(ws + 139*MB);                   // reuses x2 slot (dead by MLP time)
  float* resf   = (float*)(ws + 155*MB);
  unsigned short* statesT = (unsigned short*)(ws + 155*MB);// reuses resf slot (dead by ln3 time)
  unsigned short* resb = (unsigned short*)(ws + 171*MB);
  float* totalb = (float*)(ws + 187*MB);

  float* outf = (float*)d_out;

  // --- weight prep ---
  hipLaunchKernelGGL(transpose_cvt, dim3(32,32),  dim3(256), 0, stream, wq, wqkvgT, 1024, 1024);
  hipLaunchKernelGGL(transpose_cvt, dim3(32,32),  dim3(256), 0, stream, wk, wqkvgT + 1048576, 1024, 1024);
  hipLaunchKernelGGL(transpose_cvt, dim3(32,32),  dim3(256), 0, stream, wv, wqkvgT + 2097152, 1024, 1024);
  hipLaunchKernelGGL(transpose_cvt, dim3(32,32),  dim3(256), 0, stream, wg, wqkvgT + 3145728, 1024, 1024);
  hipLaunchKernelGGL(transpose_cvt, dim3(32,32),  dim3(256), 0, stream, wo, woT, 1024, 1024);
  hipLaunchKernelGGL(transpose_cvt, dim3(128,32), dim3(256), 0, stream, w1, w1T, 1024, 4096);
  hipLaunchKernelGGL(transpose_cvt, dim3(32,128), dim3(256), 0, stream, w2, w2T, 4096, 1024);
  hipLaunchKernelGGL(cvt_bf16x4,    dim3(4096),   dim3(256), 0, stream, cb, cbbf);
  hipLaunchKernelGGL(cbn2_kernel,   dim3(1024),   dim3(256), 0, stream, cb, cbn2);

  // --- retention sub-block ---
  hipLaunchKernelGGL(ln_kernel, dim3(4096), dim3(256), 0, stream, x, ln1_g, ln1_b, hbf, (float*)nullptr);
  hipLaunchKernelGGL((gemm_bt<3,false,false,true>), dim3(32,32), dim3(256), 0, stream,
                     hbf, wqkvgT, (void*)qbuf, (const float*)nullptr, (const float*)nullptr, 4096, 4096, 1024);
  hipLaunchKernelGGL(rope_kernel, dim3(8192), dim3(256), 0, stream, qbuf, kbuf);
  hipLaunchKernelGGL(chunk_sum,  dim3(1024), dim3(256), 0, stream, kbuf, vbuf, Tbuf);
  hipLaunchKernelGGL(chunk_scan, dim3(32),   dim3(256), 0, stream, Tbuf, statesT);
  hipLaunchKernelGGL(retention_chunk, dim3(1024), dim3(256), 0, stream,
                     qbuf, kbuf, vbuf, gbuf, statesT, ogb);
  hipLaunchKernelGGL((gemm_bt<0,false,true,false>), dim3(8,32), dim3(256), 0, stream,
                     ogb, woT, (void*)x1, (const float*)nullptr, x, 4096, 1024, 1024);

  // --- MLP sub-block ---
  hipLaunchKernelGGL(ln_kernel, dim3(4096), dim3(256), 0, stream, x1, ln2_g, ln2_b, h2, (float*)nullptr);
  hipLaunchKernelGGL((gemm_bt<2,true,false,true>), dim3(32,32), dim3(256), 0, stream,
                     h2, w1T, (void*)a1, b1, (const float*)nullptr, 4096, 4096, 1024);
  hipLaunchKernelGGL((gemm_bt<0,true,true,false>), dim3(8,32), dim3(256), 0, stream,
                     a1, w2T, (void*)x2, b2, x1, 4096, 1024, 4096);

  // --- RVQ ---
  hipLaunchKernelGGL(ln_kernel, dim3(4096), dim3(256), 0, stream, x2, ln3_g, ln3_b, resb, resf);
  for (int lvl = 0; lvl < 4; ++lvl){
    hipLaunchKernelGGL((gemm_bt<4,false,false,false>), dim3(8,32), dim3(256), 0, stream,
                       resb, cbbf + (size_t)lvl*1048576, (void*)partials,
                       cbn2 + lvl*1024, (const float*)nullptr, 4096, 1024, 1024);
    hipLaunchKernelGGL(rvq_update2, dim3(4096), dim3(256), 0, stream,
                       cb + (size_t)lvl*1048576, partials, resf, resb,
                       totalb, qlpart, lvl);
  }

  // --- outputs ---
  hipLaunchKernelGGL(final_add, dim3(2048), dim3(256), 0, stream, x2, totalb, outf);
  hipLaunchKernelGGL(ql_final, dim3(1), dim3(256), 0, stream, qlpart, outf + 4194304);
}

// Round 3
// 457.637 us; speedup vs baseline: 1.3449x; 1.1174x over previous
//
#include <hip/hip_runtime.h>
#include <cstdint>
#include <cstddef>

#define DEV __device__ __forceinline__

typedef __attribute__((ext_vector_type(8))) short bf16x8;
typedef __attribute__((ext_vector_type(4))) float f32x4;

typedef const __attribute__((address_space(1))) void gl_void;
typedef __attribute__((address_space(3))) void lds_void;

// ---------- small helpers ----------
DEV unsigned short f2bf(float f){
  union { float f; uint32_t u; } v; v.f = f;
  uint32_t r = v.u + 0x7FFFu + ((v.u >> 16) & 1u);  // RNE
  return (unsigned short)(r >> 16);
}
DEV float bf2f(unsigned short u){
  union { uint32_t u; float f; } v; v.u = ((uint32_t)u) << 16; return v.f;
}
DEV uint32_t packbf2(float a, float b){
  return (uint32_t)f2bf(a) | ((uint32_t)f2bf(b) << 16);
}

// ================= LayerNorm (fp32 in -> bf16 out, optional fp32 out) =================
__global__ void ln_kernel(const float* __restrict__ x, const float* __restrict__ gw,
                          const float* __restrict__ bw, unsigned short* __restrict__ obf,
                          float* __restrict__ of32)
{
  const int row = blockIdx.x, t = threadIdx.x;
  const float4 v = ((const float4*)(x + (size_t)row*1024))[t];
  float s  = v.x + v.y + v.z + v.w;
  float s2 = v.x*v.x + v.y*v.y + v.z*v.z + v.w*v.w;
  #pragma unroll
  for (int o = 32; o >= 1; o >>= 1){ s += __shfl_down(s, o); s2 += __shfl_down(s2, o); }
  __shared__ float red[8];
  const int w = t >> 6, ln = t & 63;
  if (ln == 0){ red[w] = s; red[4+w] = s2; }
  __syncthreads();
  const float fs  = red[0]+red[1]+red[2]+red[3];
  const float fs2 = red[4]+red[5]+red[6]+red[7];
  const float mean = fs * (1.0f/1024.0f);
  const float var  = fs2 * (1.0f/1024.0f) - mean*mean;
  const float rstd = rsqrtf(var + 1e-5f);
  const float4 gv = ((const float4*)gw)[t];
  const float4 bv = ((const float4*)bw)[t];
  float4 o4;
  o4.x = (v.x-mean)*rstd*gv.x + bv.x;
  o4.y = (v.y-mean)*rstd*gv.y + bv.y;
  o4.z = (v.z-mean)*rstd*gv.z + bv.z;
  o4.w = (v.w-mean)*rstd*gv.w + bv.w;
  if (of32) ((float4*)(of32 + (size_t)row*1024))[t] = o4;
  ushort4 ob; ob.x = f2bf(o4.x); ob.y = f2bf(o4.y); ob.z = f2bf(o4.z); ob.w = f2bf(o4.w);
  ((ushort4*)(obf + (size_t)row*1024))[t] = ob;
}

// ================= transpose + fp32->bf16  (out[C][R] = in[R][C]) =================
__global__ void transpose_cvt(const float* __restrict__ in, unsigned short* __restrict__ out,
                              int R, int C)
{
  __shared__ float tile[32][33];
  const int c0 = blockIdx.x*32, r0 = blockIdx.y*32;
  const int tx = threadIdx.x & 31, ty = threadIdx.x >> 5;   // 32 x 8
  #pragma unroll
  for (int i = 0; i < 32; i += 8)
    tile[ty+i][tx] = in[(size_t)(r0+ty+i)*C + c0 + tx];
  __syncthreads();
  #pragma unroll
  for (int i = 0; i < 32; i += 8)
    out[(size_t)(c0+ty+i)*R + r0 + tx] = f2bf(tile[tx][ty+i]);
}

// ================= fp32 -> bf16 cast (vectorized, exact grid) =================
__global__ void cvt_bf16x4(const float* __restrict__ in, unsigned short* __restrict__ out)
{
  const int i = blockIdx.x*256 + threadIdx.x;
  const float4 v = ((const float4*)in)[i];
  ushort4 o; o.x = f2bf(v.x); o.y = f2bf(v.y); o.z = f2bf(v.z); o.w = f2bf(v.w);
  ((ushort4*)out)[i] = o;
}

// ================= codebook squared norms (fp32) =================
__global__ void cbn2_kernel(const float* __restrict__ cb, float* __restrict__ cbn2)
{
  const int w = threadIdx.x >> 6, ln = threadIdx.x & 63;
  const int code = blockIdx.x*4 + w;           // 4096 codes total
  const float4* cr = (const float4*)(cb + (size_t)code*1024);
  float s = 0.f;
  for (int i = ln; i < 256; i += 64){ float4 v = cr[i]; s += v.x*v.x+v.y*v.y+v.z*v.z+v.w*v.w; }
  #pragma unroll
  for (int o = 32; o >= 1; o >>= 1) s += __shfl_down(s, o);
  if (ln == 0) cbn2[code] = s;
}

// ================= RoPE in-place on q,k (bf16) =================
__global__ void rope_kernel(unsigned short* __restrict__ q, unsigned short* __restrict__ k)
{
  const int tid = blockIdx.x*256 + threadIdx.x;        // 2*2048*16*32 = 2097152
  const int j  = tid & 31;
  const int hh = (tid >> 5) & 15;
  const int s_ = (tid >> 9) & 2047;
  const int b  = tid >> 20;
  const float inv = exp2f(-(float)j * 0.4152410118609203f);  // log2(10000)/32
  const float f = (float)s_ * inv;
  float sn, cs; sincosf(f, &sn, &cs);
  const size_t base = ((size_t)(b*2048 + s_))*1024 + hh*64 + j;
  {
    float x1 = bf2f(q[base]), x2 = bf2f(q[base+32]);
    q[base]    = f2bf(x1*cs - x2*sn);
    q[base+32] = f2bf(x2*cs + x1*sn);
  }
  {
    float x1 = bf2f(k[base]), x2 = bf2f(k[base+32]);
    k[base]    = f2bf(x1*cs - x2*sn);
    k[base+32] = f2bf(x2*cs + x1*sn);
  }
}

// ================= GEMM 128x128: C[M,N] = A[M,K] @ BT[N,K] =================
// EPI: 0 none, 1 silu, 2 gelu(exact), 3 QKVG-split (silu on sect 3).
template<int EPI, bool BIAS, bool RES, bool OUTBF>
__global__ __launch_bounds__(256, 2) void gemm_bt(
    const unsigned short* __restrict__ A, const unsigned short* __restrict__ BT,
    void* __restrict__ Cv, const float* __restrict__ bias, const float* __restrict__ resid,
    int M, int N, int K)
{
  __shared__ __align__(16) unsigned short As[2][128*32];
  __shared__ __align__(16) unsigned short Bs[2][128*32];
  const int t = threadIdx.x;
  const int w = t >> 6, ln = t & 63, lg = ln >> 4, lc = ln & 15;
  // chunked XCD swizzle (bijective; nwg % 8 == 0)
  const int gx = gridDim.x, nwg = gridDim.x * gridDim.y;
  int lin = blockIdx.y * gx + blockIdx.x;
  lin = (lin >> 3) + (lin & 7) * (nwg >> 3);
  const int m0 = (lin / gx) * 128, n0 = (lin % gx) * 128;
  const int wr = (w >> 1) * 64, wc = (w & 1) * 64;
  f32x4 acc[4][4] = {};
  const int nkt = K >> 5;

  auto stage = [&](int buf, int kt){
    #pragma unroll
    for (int c = 0; c < 2; ++c){
      const int chunk = c*256 + t;
      const int row = chunk >> 2, ke = (chunk & 3) * 8;
      __builtin_amdgcn_global_load_lds(
          (gl_void*)(A + (size_t)(m0+row)*K + (size_t)kt*32 + ke),
          (lds_void*)&As[buf][(c*256 + w*64)*8], 16, 0, 0);
      __builtin_amdgcn_global_load_lds(
          (gl_void*)(BT + (size_t)(n0+row)*K + (size_t)kt*32 + ke),
          (lds_void*)&Bs[buf][(c*256 + w*64)*8], 16, 0, 0);
    }
  };

  stage(0, 0);
  __syncthreads();
  for (int kt = 0; kt < nkt; ++kt){
    const int cur = kt & 1;
    if (kt + 1 < nkt) stage(cur ^ 1, kt + 1);
    bf16x8 af[4], bfr[4];
    #pragma unroll
    for (int i = 0; i < 4; ++i){
      af[i]  = *(const bf16x8*)&As[cur][(wr + i*16 + lc)*32 + lg*8];
      bfr[i] = *(const bf16x8*)&Bs[cur][(wc + i*16 + lc)*32 + lg*8];
    }
    #pragma unroll
    for (int m = 0; m < 4; ++m)
      #pragma unroll
      for (int n = 0; n < 4; ++n)
        acc[m][n] = __builtin_amdgcn_mfma_f32_16x16x32_bf16(af[m], bfr[n], acc[m][n], 0, 0, 0);
    __syncthreads();
  }

  #pragma unroll
  for (int m = 0; m < 4; ++m){
    #pragma unroll
    for (int n = 0; n < 4; ++n){
      #pragma unroll
      for (int r = 0; r < 4; ++r){
        const int row = m0 + wr + m*16 + lg*4 + r;
        const int col = n0 + wc + n*16 + lc;
        float v = acc[m][n][r];
        if constexpr (BIAS) v += bias[col];
        if constexpr (EPI == 1) v = v * (1.0f / (1.0f + __expf(-v)));
        if constexpr (EPI == 2) v = 0.5f * v * (1.0f + erff(v * 0.70710678118654752f));
        if constexpr (EPI == 3){
          const int sect = col >> 10;
          float ov = v;
          if (sect == 3) ov = v * (1.0f / (1.0f + __expf(-v)));
          ((unsigned short*)Cv)[(size_t)sect*4194304 + (size_t)row*1024 + (col & 1023)] = f2bf(ov);
          continue;
        }
        if constexpr (RES) v += resid[(size_t)row*N + col];
        if constexpr (OUTBF) ((unsigned short*)Cv)[(size_t)row*N + col] = f2bf(v);
        else                 ((float*)Cv)[(size_t)row*N + col] = v;
      }
    }
  }
}

// ================= GEMM 64x128 (skinny-N): more blocks, XCD-chunked =================
// EPI: 0 none, 4 argmin-partials (bias = cbn2).
template<int EPI, bool BIAS, bool RES, bool OUTBF>
__global__ __launch_bounds__(256, 2) void gemm64_bt(
    const unsigned short* __restrict__ A, const unsigned short* __restrict__ BT,
    void* __restrict__ Cv, const float* __restrict__ bias, const float* __restrict__ resid,
    int M, int N, int K)
{
  __shared__ __align__(16) unsigned short As[2][64*32];
  __shared__ __align__(16) unsigned short Bs[2][128*32];
  const int t = threadIdx.x;
  const int w = t >> 6, ln = t & 63, lg = ln >> 4, lc = ln & 15;
  // chunked XCD swizzle: all col-blocks of one row-panel land on one XCD
  const int gx = gridDim.x, nwg = gridDim.x * gridDim.y;
  int lin = blockIdx.y * gx + blockIdx.x;
  lin = (lin >> 3) + (lin & 7) * (nwg >> 3);
  const int bx = lin % gx, by = lin / gx;
  const int m0 = by * 64, n0 = bx * 128;
  const int wr = (w >> 1) * 32, wc = (w & 1) * 64;
  f32x4 acc[2][4] = {};
  const int nkt = K >> 5;

  auto stage = [&](int buf, int kt){
    {
      const int row = t >> 2, ke = (t & 3) * 8;
      __builtin_amdgcn_global_load_lds(
          (gl_void*)(A + (size_t)(m0+row)*K + (size_t)kt*32 + ke),
          (lds_void*)&As[buf][w*512], 16, 0, 0);
    }
    #pragma unroll
    for (int c = 0; c < 2; ++c){
      const int chunk = c*256 + t;
      const int row = chunk >> 2, ke = (chunk & 3) * 8;
      __builtin_amdgcn_global_load_lds(
          (gl_void*)(BT + (size_t)(n0+row)*K + (size_t)kt*32 + ke),
          (lds_void*)&Bs[buf][(c*256 + w*64)*8], 16, 0, 0);
    }
  };

  stage(0, 0);
  __syncthreads();
  for (int kt = 0; kt < nkt; ++kt){
    const int cur = kt & 1;
    if (kt + 1 < nkt) stage(cur ^ 1, kt + 1);
    bf16x8 af[2], bfr[4];
    #pragma unroll
    for (int i = 0; i < 2; ++i)
      af[i]  = *(const bf16x8*)&As[cur][(wr + i*16 + lc)*32 + lg*8];
    #pragma unroll
    for (int i = 0; i < 4; ++i)
      bfr[i] = *(const bf16x8*)&Bs[cur][(wc + i*16 + lc)*32 + lg*8];
    #pragma unroll
    for (int m = 0; m < 2; ++m)
      #pragma unroll
      for (int n = 0; n < 4; ++n)
        acc[m][n] = __builtin_amdgcn_mfma_f32_16x16x32_bf16(af[m], bfr[n], acc[m][n], 0, 0, 0);
    __syncthreads();
  }

  if constexpr (EPI == 4){
    #pragma unroll
    for (int m = 0; m < 2; ++m){
      #pragma unroll
      for (int r = 0; r < 4; ++r){
        float best = 3.4e38f; int bi = 0;
        #pragma unroll
        for (int n = 0; n < 4; ++n){
          const int col = n0 + wc + n*16 + lc;
          const float d = bias[col] - 2.0f*acc[m][n][r];
          if (d < best){ best = d; bi = col; }
        }
        #pragma unroll
        for (int o = 1; o < 16; o <<= 1){
          const float ob = __shfl_xor(best, o);
          const int oi = __shfl_xor(bi, o);
          if (ob < best || (ob == best && oi < bi)){ best = ob; bi = oi; }
        }
        if (lc == 0){
          const int row = m0 + wr + m*16 + lg*4 + r;
          ((float2*)Cv)[row*16 + bx*2 + (w & 1)] = make_float2(best, (float)bi);
        }
      }
    }
    return;
  }

  #pragma unroll
  for (int m = 0; m < 2; ++m){
    #pragma unroll
    for (int n = 0; n < 4; ++n){
      #pragma unroll
      for (int r = 0; r < 4; ++r){
        const int row = m0 + wr + m*16 + lg*4 + r;
        const int col = n0 + wc + n*16 + lc;
        float v = acc[m][n][r];
        if constexpr (BIAS) v += bias[col];
        if constexpr (RES) v += resid[(size_t)row*N + col];
        if constexpr (OUTBF) ((unsigned short*)Cv)[(size_t)row*N + col] = f2bf(v);
        else                 ((float*)Cv)[(size_t)row*N + col] = v;
      }
    }
  }
}

// ================= Chunkwise retention, C=64 =================
// Phase 1: T_c[d][dv] = sum_i gamma^(64-i) k_i[d] v_i[dv]   (fp32 out)
__global__ __launch_bounds__(256, 2) void chunk_sum(
    const unsigned short* __restrict__ kb, const unsigned short* __restrict__ vb,
    float* __restrict__ Tbuf)
{
  __shared__ unsigned short KT[64*72];
  __shared__ unsigned short VT[64*72];
  const int t = threadIdx.x, w = t >> 6, ln = t & 63, lg = ln >> 4, lc = ln & 15;
  const int blk = blockIdx.x;          // bh*32 + c
  const int bh = blk >> 5, c = blk & 31;
  const int b = bh >> 4, hh = bh & 15;
  const float lg2g = log2f(1.0f - exp2f(-5.0f - (float)hh));
  #pragma unroll
  for (int ch = 0; ch < 2; ++ch){
    const int chunk = ch*256 + t;
    const int i = chunk >> 3, d0 = (chunk & 7)*8;
    const size_t gofs = ((size_t)(b*2048 + c*64 + i))*1024 + hh*64 + d0;
    const float wi = exp2f(lg2g * (float)(64 - i));
    union {uint4 u; unsigned short s[8];} kv, vv;
    kv.u = *(const uint4*)(kb + gofs);
    vv.u = *(const uint4*)(vb + gofs);
    #pragma unroll
    for (int j = 0; j < 8; ++j){
      KT[(d0+j)*72 + i] = f2bf(bf2f(kv.s[j]) * wi);
      VT[(d0+j)*72 + i] = vv.s[j];
    }
  }
  __syncthreads();
  f32x4 acc[4] = {};
  #pragma unroll
  for (int ks = 0; ks < 2; ++ks){
    const bf16x8 af = *(const bf16x8*)&KT[(w*16 + lc)*72 + ks*32 + lg*8];
    #pragma unroll
    for (int n = 0; n < 4; ++n){
      const bf16x8 bf = *(const bf16x8*)&VT[(n*16 + lc)*72 + ks*32 + lg*8];
      acc[n] = __builtin_amdgcn_mfma_f32_16x16x32_bf16(af, bf, acc[n], 0, 0, 0);
    }
  }
  float* out = Tbuf + (size_t)blk*4096;
  #pragma unroll
  for (int n = 0; n < 4; ++n)
    #pragma unroll
    for (int r = 0; r < 4; ++r)
      out[(w*16 + lg*4 + r)*64 + n*16 + lc] = acc[n][r];
}

// Phase 2: scan S_c = gamma^64 * S_{c-1} + T_{c-1};  statesT[bh][c][dv][d] (bf16)
__global__ void chunk_scan(const float* __restrict__ Tbuf, unsigned short* __restrict__ statesT)
{
  const int bh = blockIdx.x, t = threadIdx.x;
  const int hh = bh & 15;
  const float gamma = 1.0f - exp2f(-5.0f - (float)hh);
  const float g64 = exp2f(log2f(gamma) * 64.0f);
  float S[16];
  #pragma unroll
  for (int j = 0; j < 16; ++j) S[j] = 0.f;
  const int dv = t >> 2, d0 = (t & 3) * 16;
  for (int c = 0; c < 32; ++c){
    const size_t base = ((size_t)(bh*32 + c))*4096;
    union { unsigned short s[8]; uint4 u; } p0, p1;
    #pragma unroll
    for (int j = 0; j < 8; ++j){ p0.s[j] = f2bf(S[j]); p1.s[j] = f2bf(S[8+j]); }
    *(uint4*)(statesT + base + t*16)     = p0.u;
    *(uint4*)(statesT + base + t*16 + 8) = p1.u;
    #pragma unroll
    for (int j = 0; j < 16; ++j)
      S[j] = g64*S[j] + Tbuf[base + (size_t)(d0 + j)*64 + dv];
  }
}

// Phase 3: per chunk: O = decay.(QK^T/8) V + diag(gamma^i) (Q S_c)/8 ; og = O*g
__global__ __launch_bounds__(256, 2) void retention_chunk(
    const unsigned short* __restrict__ qb, const unsigned short* __restrict__ kb,
    const unsigned short* __restrict__ vb, const unsigned short* __restrict__ gb,
    const unsigned short* __restrict__ statesT, unsigned short* __restrict__ og)
{
  __shared__ unsigned short VT[64*72];
  __shared__ unsigned short Pw[64*72];
  const int t = threadIdx.x, w = t >> 6, ln = t & 63, lg = ln >> 4, lc = ln & 15;
  const int blk = blockIdx.x;          // bh*32 + c
  const int bh = blk >> 5, c = blk & 31;
  const int b = bh >> 4, hh = bh & 15;
  const float lg2g = log2f(1.0f - exp2f(-5.0f - (float)hh));
  float gpr[4];
  #pragma unroll
  for (int r = 0; r < 4; ++r) gpr[r] = exp2f(-lg2g * (float)r);   // gamma^{-r}
  const size_t rowbase = (size_t)(b*2048 + c*64);

  #pragma unroll
  for (int ch = 0; ch < 2; ++ch){
    const int chunk = ch*256 + t;
    const int i = chunk >> 3, d0 = (chunk & 7)*8;
    union {uint4 u; unsigned short s[8];} vv;
    vv.u = *(const uint4*)(vb + (rowbase + i)*1024 + hh*64 + d0);
    #pragma unroll
    for (int j = 0; j < 8; ++j) VT[(d0+j)*72 + i] = vv.s[j];
  }

  bf16x8 Qf[2], Kf[4][2];
  #pragma unroll
  for (int ks = 0; ks < 2; ++ks){
    union {uint4 u; bf16x8 f;} cv;
    cv.u = *(const uint4*)(qb + (rowbase + w*16 + lc)*1024 + hh*64 + ks*32 + lg*8);
    Qf[ks] = cv.f;
    #pragma unroll
    for (int mt = 0; mt < 4; ++mt){
      union {uint4 u; bf16x8 f;} kv;
      kv.u = *(const uint4*)(kb + (rowbase + mt*16 + lc)*1024 + hh*64 + ks*32 + lg*8);
      Kf[mt][ks] = kv.f;
    }
  }

  f32x4 st[4] = {};
  #pragma unroll
  for (int ks = 0; ks < 2; ++ks)
    #pragma unroll
    for (int mt = 0; mt < 4; ++mt)
      st[mt] = __builtin_amdgcn_mfma_f32_16x16x32_bf16(Kf[mt][ks], Qf[ks], st[mt], 0, 0, 0);

  __syncthreads();

  #pragma unroll
  for (int mt = 0; mt < 4; ++mt){
    const int kp = mt*16 + lg*4;
    const int qrow = w*16 + lc;
    const int delta0 = qrow - kp;
    const float dec0 = exp2f(lg2g * (float)delta0) * 0.125f;
    float vals[4];
    #pragma unroll
    for (int r = 0; r < 4; ++r)
      vals[r] = (delta0 >= r) ? st[mt][r] * dec0 * gpr[r] : 0.0f;
    uint2 pk; pk.x = packbf2(vals[0], vals[1]); pk.y = packbf2(vals[2], vals[3]);
    *(uint2*)&Pw[qrow*72 + kp] = pk;
  }

  f32x4 acc[4] = {};
  const unsigned short* Sbase = statesT + (size_t)blk*4096;
  #pragma unroll
  for (int ks = 0; ks < 2; ++ks)
    #pragma unroll
    for (int n = 0; n < 4; ++n){
      union {uint4 u; bf16x8 f;} sv;
      sv.u = *(const uint4*)(Sbase + (n*16 + lc)*64 + ks*32 + lg*8);
      acc[n] = __builtin_amdgcn_mfma_f32_16x16x32_bf16(Qf[ks], sv.f, acc[n], 0, 0, 0);
    }
  #pragma unroll
  for (int n = 0; n < 4; ++n)
    #pragma unroll
    for (int r = 0; r < 4; ++r)
      acc[n][r] *= exp2f(lg2g * (float)(w*16 + lg*4 + r)) * 0.125f;

  #pragma unroll
  for (int ks = 0; ks < 2; ++ks){
    const bf16x8 Pf = *(const bf16x8*)&Pw[(w*16 + lc)*72 + ks*32 + lg*8];
    #pragma unroll
    for (int n = 0; n < 4; ++n){
      const bf16x8 Vf = *(const bf16x8*)&VT[(n*16 + lc)*72 + ks*32 + lg*8];
      acc[n] = __builtin_amdgcn_mfma_f32_16x16x32_bf16(Pf, Vf, acc[n], 0, 0, 0);
    }
  }

  #pragma unroll
  for (int n = 0; n < 4; ++n){
    #pragma unroll
    for (int r = 0; r < 4; ++r){
      const size_t row = rowbase + w*16 + lg*4 + r;
      const int col = hh*64 + n*16 + lc;
      const float gv = bf2f(gb[row*1024 + col]);
      og[row*1024 + col] = f2bf(acc[n][r] * gv);
    }
  }
}

// ================= RVQ: argmin-from-partials + residual/total update =================
__global__ void rvq_update2(const float* __restrict__ cb_l, const float2* __restrict__ partials,
                            float* __restrict__ res, unsigned short* __restrict__ resb,
                            float* __restrict__ total, float* __restrict__ qlpart, int lvl)
{
  const int m = blockIdx.x, t = threadIdx.x;
  __shared__ int sid;
  if (t == 0){
    float best = 3.4e38f; int bi = 0;
    #pragma unroll
    for (int p = 0; p < 16; ++p){
      const float2 pr = partials[m*16 + p];
      if (pr.x < best){ best = pr.x; bi = (int)pr.y; }
    }
    sid = bi;
  }
  __syncthreads();
  const int id = sid;
  const float4 qv = ((const float4*)(cb_l + (size_t)id*1024))[t];
  const float4 rv = ((const float4*)(res + (size_t)m*1024))[t];
  float4 nr; nr.x = rv.x - qv.x; nr.y = rv.y - qv.y; nr.z = rv.z - qv.z; nr.w = rv.w - qv.w;
  float4 tv;
  if (lvl == 0){ tv = qv; }
  else { tv = ((const float4*)(total + (size_t)m*1024))[t];
         tv.x += qv.x; tv.y += qv.y; tv.z += qv.z; tv.w += qv.w; }
  ((float4*)(total + (size_t)m*1024))[t] = tv;
  ((float4*)(res   + (size_t)m*1024))[t] = nr;
  ushort4 nb; nb.x = f2bf(nr.x); nb.y = f2bf(nr.y); nb.z = f2bf(nr.z); nb.w = f2bf(nr.w);
  ((ushort4*)(resb + (size_t)m*1024))[t] = nb;
  float s = nr.x*nr.x + nr.y*nr.y + nr.z*nr.z + nr.w*nr.w;
  #pragma unroll
  for (int o = 32; o >= 1; o >>= 1) s += __shfl_down(s, o);
  __shared__ float red[4];
  if ((t & 63) == 0) red[t >> 6] = s;
  __syncthreads();
  if (t == 0) qlpart[lvl*4096 + m] = red[0]+red[1]+red[2]+red[3];
}

// ================= finals =================
__global__ void final_add(const float* __restrict__ x2, const float* __restrict__ total,
                          float* __restrict__ out)
{
  int i = blockIdx.x*256 + threadIdx.x;
  const float4* a = (const float4*)x2;
  const float4* b = (const float4*)total;
  float4* o = (float4*)out;
  for (; i < 4194304/4; i += gridDim.x*256){
    float4 va = a[i], vb = b[i];
    va.x += vb.x; va.y += vb.y; va.z += vb.z; va.w += vb.w;
    o[i] = va;
  }
}

__global__ void ql_final(const float* __restrict__ qlpart, float* __restrict__ outs)
{
  const int t = threadIdx.x;
  float s = 0.f;
  for (int i = t; i < 16384; i += 256) s += qlpart[i];
  #pragma unroll
  for (int o = 32; o >= 1; o >>= 1) s += __shfl_down(s, o);
  __shared__ float red[4];
  if ((t & 63) == 0) red[t >> 6] = s;
  __syncthreads();
  if (t == 0){
    const float q = (red[0]+red[1]+red[2]+red[3]) * (1.0f/4194304.0f) * 0.25f;
    outs[0] = q; outs[1] = q;
  }
}

// ================= launcher =================
extern "C" void kernel_launch(void* const* d_in, const int* in_sizes, int n_in,
                              void* d_out, int out_size, void* d_ws, size_t ws_size,
                              hipStream_t stream)
{
  const float* x     = (const float*)d_in[0];
  const float* ln1_g = (const float*)d_in[1];
  const float* ln1_b = (const float*)d_in[2];
  const float* wq    = (const float*)d_in[3];
  const float* wk    = (const float*)d_in[4];
  const float* wv    = (const float*)d_in[5];
  const float* wg    = (const float*)d_in[6];
  const float* wo    = (const float*)d_in[7];
  const float* ln2_g = (const float*)d_in[8];
  const float* ln2_b = (const float*)d_in[9];
  const float* w1    = (const float*)d_in[10];
  const float* b1    = (const float*)d_in[11];
  const float* w2    = (const float*)d_in[12];
  const float* b2    = (const float*)d_in[13];
  const float* ln3_g = (const float*)d_in[14];
  const float* ln3_b = (const float*)d_in[15];
  const float* cb    = (const float*)d_in[16];

  char* ws = (char*)d_ws;
  const size_t MB = 1024*1024;
  unsigned short* wqkvgT = (unsigned short*)(ws + 0*MB);   // wq^T,wk^T,wv^T,wg^T contiguous [4096][1024]
  unsigned short* woT  = (unsigned short*)(ws + 8*MB);
  unsigned short* w1T  = (unsigned short*)(ws + 10*MB);
  unsigned short* w2T  = (unsigned short*)(ws + 18*MB);
  unsigned short* cbbf = (unsigned short*)(ws + 26*MB);
  float* cbn2     = (float*)(ws + 34*MB);                  // 16KB
  float* qlpart   = (float*)(ws + 34*MB + 16*1024);        // 64KB
  float2* partials= (float2*)(ws + 34*MB + 128*1024);      // 512KB
  unsigned short* hbf  = (unsigned short*)(ws + 35*MB);
  unsigned short* qbuf = (unsigned short*)(ws + 43*MB);
  unsigned short* kbuf = (unsigned short*)(ws + 51*MB);
  unsigned short* vbuf = (unsigned short*)(ws + 59*MB);
  unsigned short* gbuf = (unsigned short*)(ws + 67*MB);
  unsigned short* ogb  = (unsigned short*)(ws + 75*MB);
  float* x1     = (float*)(ws + 83*MB);
  unsigned short* h2   = (unsigned short*)(ws + 99*MB);
  unsigned short* a1   = (unsigned short*)(ws + 107*MB);
  float* x2     = (float*)(ws + 139*MB);
  float* Tbuf   = (float*)(ws + 139*MB);                   // reuses x2 slot (dead by MLP time)
  float* resf   = (float*)(ws + 155*MB);
  unsigned short* statesT = (unsigned short*)(ws + 155*MB);// reuses resf slot (dead by ln3 time)
  unsigned short* resb = (unsigned short*)(ws + 171*MB);
  float* totalb = (float*)(ws + 187*MB);

  float* outf = (float*)d_out;

  // --- weight prep ---
  hipLaunchKernelGGL(transpose_cvt, dim3(32,32),  dim3(256), 0, stream, wq, wqkvgT, 1024, 1024);
  hipLaunchKernelGGL(transpose_cvt, dim3(32,32),  dim3(256), 0, stream, wk, wqkvgT + 1048576, 1024, 1024);
  hipLaunchKernelGGL(transpose_cvt, dim3(32,32),  dim3(256), 0, stream, wv, wqkvgT + 2097152, 1024, 1024);
  hipLaunchKernelGGL(transpose_cvt, dim3(32,32),  dim3(256), 0, stream, wg, wqkvgT + 3145728, 1024, 1024);
  hipLaunchKernelGGL(transpose_cvt, dim3(32,32),  dim3(256), 0, stream, wo, woT, 1024, 1024);
  hipLaunchKernelGGL(transpose_cvt, dim3(128,32), dim3(256), 0, stream, w1, w1T, 1024, 4096);
  hipLaunchKernelGGL(transpose_cvt, dim3(32,128), dim3(256), 0, stream, w2, w2T, 4096, 1024);
  hipLaunchKernelGGL(cvt_bf16x4,    dim3(4096),   dim3(256), 0, stream, cb, cbbf);
  hipLaunchKernelGGL(cbn2_kernel,   dim3(1024),   dim3(256), 0, stream, cb, cbn2);

  // --- retention sub-block ---
  hipLaunchKernelGGL(ln_kernel, dim3(4096), dim3(256), 0, stream, x, ln1_g, ln1_b, hbf, (float*)nullptr);
  hipLaunchKernelGGL((gemm_bt<3,false,false,true>), dim3(32,32), dim3(256), 0, stream,
                     hbf, wqkvgT, (void*)qbuf, (const float*)nullptr, (const float*)nullptr, 4096, 4096, 1024);
  hipLaunchKernelGGL(rope_kernel, dim3(8192), dim3(256), 0, stream, qbuf, kbuf);
  hipLaunchKernelGGL(chunk_sum,  dim3(1024), dim3(256), 0, stream, kbuf, vbuf, Tbuf);
  hipLaunchKernelGGL(chunk_scan, dim3(32),   dim3(256), 0, stream, Tbuf, statesT);
  hipLaunchKernelGGL(retention_chunk, dim3(1024), dim3(256), 0, stream,
                     qbuf, kbuf, vbuf, gbuf, statesT, ogb);
  hipLaunchKernelGGL((gemm64_bt<0,false,true,false>), dim3(8,64), dim3(256), 0, stream,
                     ogb, woT, (void*)x1, (const float*)nullptr, x, 4096, 1024, 1024);

  // --- MLP sub-block ---
  hipLaunchKernelGGL(ln_kernel, dim3(4096), dim3(256), 0, stream, x1, ln2_g, ln2_b, h2, (float*)nullptr);
  hipLaunchKernelGGL((gemm_bt<2,true,false,true>), dim3(32,32), dim3(256), 0, stream,
                     h2, w1T, (void*)a1, b1, (const float*)nullptr, 4096, 4096, 1024);
  hipLaunchKernelGGL((gemm64_bt<0,true,true,false>), dim3(8,64), dim3(256), 0, stream,
                     a1, w2T, (void*)x2, b2, x1, 4096, 1024, 4096);

  // --- RVQ ---
  hipLaunchKernelGGL(ln_kernel, dim3(4096), dim3(256), 0, stream, x2, ln3_g, ln3_b, resb, resf);
  for (int lvl = 0; lvl < 4; ++lvl){
    hipLaunchKernelGGL((gemm64_bt<4,false,false,false>), dim3(8,64), dim3(256), 0, stream,
                       resb, cbbf + (size_t)lvl*1048576, (void*)partials,
                       cbn2 + lvl*1024, (const float*)nullptr, 4096, 1024, 1024);
    hipLaunchKernelGGL(rvq_update2, dim3(4096), dim3(256), 0, stream,
                       cb + (size_t)lvl*1048576, partials, resf, resb,
                       totalb, qlpart, lvl);
  }

  // --- outputs ---
  hipLaunchKernelGGL(final_add, dim3(2048), dim3(256), 0, stream, x2, totalb, outf);
  hipLaunchKernelGGL(ql_final, dim3(1), dim3(256), 0, stream, qlpart, outf + 4194304);
}

// Round 4
// 443.643 us; speedup vs baseline: 1.3873x; 1.0315x over previous
//
#include <hip/hip_runtime.h>
#include <cstdint>
#include <cstddef>

#define DEV __device__ __forceinline__

typedef __attribute__((ext_vector_type(8))) short bf16x8;
typedef __attribute__((ext_vector_type(4))) float f32x4;

typedef const __attribute__((address_space(1))) void gl_void;
typedef __attribute__((address_space(3))) void lds_void;

// ---------- small helpers ----------
DEV unsigned short f2bf(float f){
  union { float f; uint32_t u; } v; v.f = f;
  uint32_t r = v.u + 0x7FFFu + ((v.u >> 16) & 1u);  // RNE
  return (unsigned short)(r >> 16);
}
DEV float bf2f(unsigned short u){
  union { uint32_t u; float f; } v; v.u = ((uint32_t)u) << 16; return v.f;
}
DEV uint32_t packbf2(float a, float b){
  return (uint32_t)f2bf(a) | ((uint32_t)f2bf(b) << 16);
}

// ================= LayerNorm (fp32 in -> bf16 out, optional fp32 out) =================
__global__ void ln_kernel(const float* __restrict__ x, const float* __restrict__ gw,
                          const float* __restrict__ bw, unsigned short* __restrict__ obf,
                          float* __restrict__ of32)
{
  const int row = blockIdx.x, t = threadIdx.x;
  const float4 v = ((const float4*)(x + (size_t)row*1024))[t];
  float s  = v.x + v.y + v.z + v.w;
  float s2 = v.x*v.x + v.y*v.y + v.z*v.z + v.w*v.w;
  #pragma unroll
  for (int o = 32; o >= 1; o >>= 1){ s += __shfl_down(s, o); s2 += __shfl_down(s2, o); }
  __shared__ float red[8];
  const int w = t >> 6, ln = t & 63;
  if (ln == 0){ red[w] = s; red[4+w] = s2; }
  __syncthreads();
  const float fs  = red[0]+red[1]+red[2]+red[3];
  const float fs2 = red[4]+red[5]+red[6]+red[7];
  const float mean = fs * (1.0f/1024.0f);
  const float var  = fs2 * (1.0f/1024.0f) - mean*mean;
  const float rstd = rsqrtf(var + 1e-5f);
  const float4 gv = ((const float4*)gw)[t];
  const float4 bv = ((const float4*)bw)[t];
  float4 o4;
  o4.x = (v.x-mean)*rstd*gv.x + bv.x;
  o4.y = (v.y-mean)*rstd*gv.y + bv.y;
  o4.z = (v.z-mean)*rstd*gv.z + bv.z;
  o4.w = (v.w-mean)*rstd*gv.w + bv.w;
  if (of32) ((float4*)(of32 + (size_t)row*1024))[t] = o4;
  ushort4 ob; ob.x = f2bf(o4.x); ob.y = f2bf(o4.y); ob.z = f2bf(o4.z); ob.w = f2bf(o4.w);
  ((ushort4*)(obf + (size_t)row*1024))[t] = ob;
}

// ================= batched transpose + fp32->bf16 (5x 1024x1024), out contiguous ==========
struct Ptr5 { const float* p[5]; };
__global__ void transpose_cvt5(Ptr5 in, unsigned short* __restrict__ out)
{
  __shared__ float tile[32][33];
  const float* src = in.p[blockIdx.z];
  unsigned short* dst = out + (size_t)blockIdx.z*1048576;
  const int c0 = blockIdx.x*32, r0 = blockIdx.y*32;
  const int tx = threadIdx.x & 31, ty = threadIdx.x >> 5;   // 32 x 8
  #pragma unroll
  for (int i = 0; i < 32; i += 8)
    tile[ty+i][tx] = src[(size_t)(r0+ty+i)*1024 + c0 + tx];
  __syncthreads();
  #pragma unroll
  for (int i = 0; i < 32; i += 8)
    dst[(size_t)(c0+ty+i)*1024 + r0 + tx] = f2bf(tile[tx][ty+i]);
}

// ================= transpose + fp32->bf16  (out[C][R] = in[R][C]) =================
__global__ void transpose_cvt(const float* __restrict__ in, unsigned short* __restrict__ out,
                              int R, int C)
{
  __shared__ float tile[32][33];
  const int c0 = blockIdx.x*32, r0 = blockIdx.y*32;
  const int tx = threadIdx.x & 31, ty = threadIdx.x >> 5;   // 32 x 8
  #pragma unroll
  for (int i = 0; i < 32; i += 8)
    tile[ty+i][tx] = in[(size_t)(r0+ty+i)*C + c0 + tx];
  __syncthreads();
  #pragma unroll
  for (int i = 0; i < 32; i += 8)
    out[(size_t)(c0+ty+i)*R + r0 + tx] = f2bf(tile[tx][ty+i]);
}

// ================= fp32 -> bf16 cast (vectorized, exact grid) =================
__global__ void cvt_bf16x4(const float* __restrict__ in, unsigned short* __restrict__ out)
{
  const int i = blockIdx.x*256 + threadIdx.x;
  const float4 v = ((const float4*)in)[i];
  ushort4 o; o.x = f2bf(v.x); o.y = f2bf(v.y); o.z = f2bf(v.z); o.w = f2bf(v.w);
  ((ushort4*)out)[i] = o;
}

// ================= codebook squared norms (fp32) =================
__global__ void cbn2_kernel(const float* __restrict__ cb, float* __restrict__ cbn2)
{
  const int w = threadIdx.x >> 6, ln = threadIdx.x & 63;
  const int code = blockIdx.x*4 + w;           // 4096 codes total
  const float4* cr = (const float4*)(cb + (size_t)code*1024);
  float s = 0.f;
  for (int i = ln; i < 256; i += 64){ float4 v = cr[i]; s += v.x*v.x+v.y*v.y+v.z*v.z+v.w*v.w; }
  #pragma unroll
  for (int o = 32; o >= 1; o >>= 1) s += __shfl_down(s, o);
  if (ln == 0) cbn2[code] = s;
}

// ================= RoPE in-place on q,k (bf16) =================
__global__ void rope_kernel(unsigned short* __restrict__ q, unsigned short* __restrict__ k)
{
  const int tid = blockIdx.x*256 + threadIdx.x;        // 2*2048*16*32 = 2097152
  const int j  = tid & 31;
  const int hh = (tid >> 5) & 15;
  const int s_ = (tid >> 9) & 2047;
  const int b  = tid >> 20;
  const float inv = exp2f(-(float)j * 0.4152410118609203f);  // log2(10000)/32
  const float f = (float)s_ * inv;
  float sn, cs; sincosf(f, &sn, &cs);
  const size_t base = ((size_t)(b*2048 + s_))*1024 + hh*64 + j;
  {
    float x1 = bf2f(q[base]), x2 = bf2f(q[base+32]);
    q[base]    = f2bf(x1*cs - x2*sn);
    q[base+32] = f2bf(x2*cs + x1*sn);
  }
  {
    float x1 = bf2f(k[base]), x2 = bf2f(k[base+32]);
    k[base]    = f2bf(x1*cs - x2*sn);
    k[base+32] = f2bf(x2*cs + x1*sn);
  }
}

// ================= GEMM 128x128, BK=64, XOR-swizzled LDS =================
// EPI: 0 none, 1 silu, 2 gelu(exact), 3 QKVG-split (silu on sect 3).
template<int EPI, bool BIAS, bool RES, bool OUTBF>
__global__ __launch_bounds__(256, 2) void gemm_bt(
    const unsigned short* __restrict__ A, const unsigned short* __restrict__ BT,
    void* __restrict__ Cv, const float* __restrict__ bias, const float* __restrict__ resid,
    int M, int N, int K)
{
  __shared__ __align__(16) unsigned short As[2][128*64];
  __shared__ __align__(16) unsigned short Bs[2][128*64];
  const int t = threadIdx.x;
  const int w = t >> 6, ln = t & 63, lg = ln >> 4, lc = ln & 15;
  // chunked XCD swizzle (bijective; nwg % 8 == 0)
  const int gx = gridDim.x, nwg = gridDim.x * gridDim.y;
  int lin = blockIdx.y * gx + blockIdx.x;
  lin = (lin >> 3) + (lin & 7) * (nwg >> 3);
  const int m0 = (lin / gx) * 128, n0 = (lin % gx) * 128;
  const int wr = (w >> 1) * 64, wc = (w & 1) * 64;
  f32x4 acc[4][4] = {};
  const int nkt = K >> 6;

  auto stage = [&](int buf, int kt){
    #pragma unroll
    for (int c = 0; c < 4; ++c){
      const int chunk = c*256 + t;
      const int row = chunk >> 3;
      const int kb = (((chunk & 7) << 4) ^ ((row & 7) << 4)) >> 1;  // swizzled elem-col
      __builtin_amdgcn_global_load_lds(
          (gl_void*)(A + (size_t)(m0+row)*K + (size_t)kt*64 + kb),
          (lds_void*)&As[buf][(c*256 + w*64)*8], 16, 0, 0);
      __builtin_amdgcn_global_load_lds(
          (gl_void*)(BT + (size_t)(n0+row)*K + (size_t)kt*64 + kb),
          (lds_void*)&Bs[buf][(c*256 + w*64)*8], 16, 0, 0);
    }
  };

  stage(0, 0);
  __syncthreads();
  for (int kt = 0; kt < nkt; ++kt){
    const int cur = kt & 1;
    if (kt + 1 < nkt) stage(cur ^ 1, kt + 1);
    #pragma unroll
    for (int ks = 0; ks < 2; ++ks){
      bf16x8 af[4], bfr[4];
      #pragma unroll
      for (int i = 0; i < 4; ++i){
        const int rowA = wr + i*16 + lc;
        const int rowB = wc + i*16 + lc;
        const int colA = (((ks<<6) + (lg<<4)) ^ ((rowA & 7) << 4)) >> 1;
        const int colB = (((ks<<6) + (lg<<4)) ^ ((rowB & 7) << 4)) >> 1;
        af[i]  = *(const bf16x8*)&As[cur][rowA*64 + colA];
        bfr[i] = *(const bf16x8*)&Bs[cur][rowB*64 + colB];
      }
      #pragma unroll
      for (int m = 0; m < 4; ++m)
        #pragma unroll
        for (int n = 0; n < 4; ++n)
          acc[m][n] = __builtin_amdgcn_mfma_f32_16x16x32_bf16(af[m], bfr[n], acc[m][n], 0, 0, 0);
    }
    __syncthreads();
  }

  #pragma unroll
  for (int m = 0; m < 4; ++m){
    #pragma unroll
    for (int n = 0; n < 4; ++n){
      #pragma unroll
      for (int r = 0; r < 4; ++r){
        const int row = m0 + wr + m*16 + lg*4 + r;
        const int col = n0 + wc + n*16 + lc;
        float v = acc[m][n][r];
        if constexpr (BIAS) v += bias[col];
        if constexpr (EPI == 1) v = v * (1.0f / (1.0f + __expf(-v)));
        if constexpr (EPI == 2) v = 0.5f * v * (1.0f + erff(v * 0.70710678118654752f));
        if constexpr (EPI == 3){
          const int sect = col >> 10;
          float ov = v;
          if (sect == 3) ov = v * (1.0f / (1.0f + __expf(-v)));
          ((unsigned short*)Cv)[(size_t)sect*4194304 + (size_t)row*1024 + (col & 1023)] = f2bf(ov);
          continue;
        }
        if constexpr (RES) v += resid[(size_t)row*N + col];
        if constexpr (OUTBF) ((unsigned short*)Cv)[(size_t)row*N + col] = f2bf(v);
        else                 ((float*)Cv)[(size_t)row*N + col] = v;
      }
    }
  }
}

// ================= GEMM 64x128, BK=64, swizzled; optional split-K =================
// EPI: 0 none, 4 argmin-partials (bias = cbn2).
template<int EPI, bool BIAS, bool RES, bool OUTBF, int NSPLIT>
__global__ __launch_bounds__(256, 3) void gemm64_bt(
    const unsigned short* __restrict__ A, const unsigned short* __restrict__ BT,
    void* __restrict__ Cv, const float* __restrict__ bias, const float* __restrict__ resid,
    int M, int N, int K)
{
  __shared__ __align__(16) unsigned short As[2][64*64];
  __shared__ __align__(16) unsigned short Bs[2][128*64];
  const int t = threadIdx.x;
  const int w = t >> 6, ln = t & 63, lg = ln >> 4, lc = ln & 15;
  const int gx = gridDim.x, nwg = gridDim.x * gridDim.y;
  int lin = blockIdx.y * gx + blockIdx.x;
  lin = (lin >> 3) + (lin & 7) * (nwg >> 3);
  const int bx = lin % gx, by = lin / gx;
  const int m0 = by * 64, n0 = bx * 128;
  const int wr = (w >> 1) * 32, wc = (w & 1) * 64;
  f32x4 acc[2][4] = {};
  const int nkt = (K >> 6) / NSPLIT;
  const int ktb = (NSPLIT > 1) ? blockIdx.z * nkt : 0;

  auto stage = [&](int buf, int kt){
    {
      const int chunk = t;                       // 2 chunks of A handled by first loop below
    }
    #pragma unroll
    for (int c = 0; c < 2; ++c){
      const int chunk = c*256 + t;
      const int row = chunk >> 3;
      const int kb = (((chunk & 7) << 4) ^ ((row & 7) << 4)) >> 1;
      __builtin_amdgcn_global_load_lds(
          (gl_void*)(A + (size_t)(m0+row)*K + (size_t)(ktb+kt)*64 + kb),
          (lds_void*)&As[buf][(c*256 + w*64)*8], 16, 0, 0);
    }
    #pragma unroll
    for (int c = 0; c < 4; ++c){
      const int chunk = c*256 + t;
      const int row = chunk >> 3;
      const int kb = (((chunk & 7) << 4) ^ ((row & 7) << 4)) >> 1;
      __builtin_amdgcn_global_load_lds(
          (gl_void*)(BT + (size_t)(n0+row)*K + (size_t)(ktb+kt)*64 + kb),
          (lds_void*)&Bs[buf][(c*256 + w*64)*8], 16, 0, 0);
    }
  };

  stage(0, 0);
  __syncthreads();
  for (int kt = 0; kt < nkt; ++kt){
    const int cur = kt & 1;
    if (kt + 1 < nkt) stage(cur ^ 1, kt + 1);
    #pragma unroll
    for (int ks = 0; ks < 2; ++ks){
      bf16x8 af[2], bfr[4];
      #pragma unroll
      for (int i = 0; i < 2; ++i){
        const int rowA = wr + i*16 + lc;
        const int colA = (((ks<<6) + (lg<<4)) ^ ((rowA & 7) << 4)) >> 1;
        af[i] = *(const bf16x8*)&As[cur][rowA*64 + colA];
      }
      #pragma unroll
      for (int i = 0; i < 4; ++i){
        const int rowB = wc + i*16 + lc;
        const int colB = (((ks<<6) + (lg<<4)) ^ ((rowB & 7) << 4)) >> 1;
        bfr[i] = *(const bf16x8*)&Bs[cur][rowB*64 + colB];
      }
      #pragma unroll
      for (int m = 0; m < 2; ++m)
        #pragma unroll
        for (int n = 0; n < 4; ++n)
          acc[m][n] = __builtin_amdgcn_mfma_f32_16x16x32_bf16(af[m], bfr[n], acc[m][n], 0, 0, 0);
    }
    __syncthreads();
  }

  if constexpr (EPI == 4){
    #pragma unroll
    for (int m = 0; m < 2; ++m){
      #pragma unroll
      for (int r = 0; r < 4; ++r){
        float best = 3.4e38f; int bi = 0;
        #pragma unroll
        for (int n = 0; n < 4; ++n){
          const int col = n0 + wc + n*16 + lc;
          const float d = bias[col] - 2.0f*acc[m][n][r];
          if (d < best){ best = d; bi = col; }
        }
        #pragma unroll
        for (int o = 1; o < 16; o <<= 1){
          const float ob = __shfl_xor(best, o);
          const int oi = __shfl_xor(bi, o);
          if (ob < best || (ob == best && oi < bi)){ best = ob; bi = oi; }
        }
        if (lc == 0){
          const int row = m0 + wr + m*16 + lg*4 + r;
          ((float2*)Cv)[row*16 + bx*2 + (w & 1)] = make_float2(best, (float)bi);
        }
      }
    }
    return;
  }

  float* Cp = (float*)Cv + (NSPLIT > 1 ? (size_t)blockIdx.z * (size_t)M * N : 0);
  #pragma unroll
  for (int m = 0; m < 2; ++m){
    #pragma unroll
    for (int n = 0; n < 4; ++n){
      #pragma unroll
      for (int r = 0; r < 4; ++r){
        const int row = m0 + wr + m*16 + lg*4 + r;
        const int col = n0 + wc + n*16 + lc;
        float v = acc[m][n][r];
        if constexpr (BIAS) v += bias[col];
        if constexpr (RES) v += resid[(size_t)row*N + col];
        if constexpr (OUTBF) ((unsigned short*)Cv)[(size_t)row*N + col] = f2bf(v);
        else                 Cp[(size_t)row*N + col] = v;
      }
    }
  }
}

// ================= split-K reduce: out = p0 + p1 + bias + resid =================
__global__ void splitk_reduce(const float* __restrict__ p, const float* __restrict__ bias,
                              const float* __restrict__ resid, float* __restrict__ out)
{
  const int i = blockIdx.x*256 + threadIdx.x;   // float4 index over 4096*1024/4
  const float4 a = ((const float4*)p)[i];
  const float4 b = ((const float4*)(p + 4194304))[i];
  const float4 rv = ((const float4*)resid)[i];
  const float4 bv = ((const float4*)bias)[i & 255];
  float4 o;
  o.x = a.x + b.x + rv.x + bv.x;
  o.y = a.y + b.y + rv.y + bv.y;
  o.z = a.z + b.z + rv.z + bv.z;
  o.w = a.w + b.w + rv.w + bv.w;
  ((float4*)out)[i] = o;
}

// ================= Chunkwise retention, C=64 =================
__global__ __launch_bounds__(256, 2) void chunk_sum(
    const unsigned short* __restrict__ kb, const unsigned short* __restrict__ vb,
    float* __restrict__ Tbuf)
{
  __shared__ unsigned short KT[64*72];
  __shared__ unsigned short VT[64*72];
  const int t = threadIdx.x, w = t >> 6, ln = t & 63, lg = ln >> 4, lc = ln & 15;
  const int blk = blockIdx.x;          // bh*32 + c
  const int bh = blk >> 5, c = blk & 31;
  const int b = bh >> 4, hh = bh & 15;
  const float lg2g = log2f(1.0f - exp2f(-5.0f - (float)hh));
  #pragma unroll
  for (int ch = 0; ch < 2; ++ch){
    const int chunk = ch*256 + t;
    const int i = chunk >> 3, d0 = (chunk & 7)*8;
    const size_t gofs = ((size_t)(b*2048 + c*64 + i))*1024 + hh*64 + d0;
    const float wi = exp2f(lg2g * (float)(64 - i));
    union {uint4 u; unsigned short s[8];} kv, vv;
    kv.u = *(const uint4*)(kb + gofs);
    vv.u = *(const uint4*)(vb + gofs);
    #pragma unroll
    for (int j = 0; j < 8; ++j){
      KT[(d0+j)*72 + i] = f2bf(bf2f(kv.s[j]) * wi);
      VT[(d0+j)*72 + i] = vv.s[j];
    }
  }
  __syncthreads();
  f32x4 acc[4] = {};
  #pragma unroll
  for (int ks = 0; ks < 2; ++ks){
    const bf16x8 af = *(const bf16x8*)&KT[(w*16 + lc)*72 + ks*32 + lg*8];
    #pragma unroll
    for (int n = 0; n < 4; ++n){
      const bf16x8 bf = *(const bf16x8*)&VT[(n*16 + lc)*72 + ks*32 + lg*8];
      acc[n] = __builtin_amdgcn_mfma_f32_16x16x32_bf16(af, bf, acc[n], 0, 0, 0);
    }
  }
  float* out = Tbuf + (size_t)blk*4096;
  #pragma unroll
  for (int n = 0; n < 4; ++n)
    #pragma unroll
    for (int r = 0; r < 4; ++r)
      out[(w*16 + lg*4 + r)*64 + n*16 + lc] = acc[n][r];
}

__global__ void chunk_scan(const float* __restrict__ Tbuf, unsigned short* __restrict__ statesT)
{
  const int bh = blockIdx.x, t = threadIdx.x;
  const int hh = bh & 15;
  const float gamma = 1.0f - exp2f(-5.0f - (float)hh);
  const float g64 = exp2f(log2f(gamma) * 64.0f);
  float S[16];
  #pragma unroll
  for (int j = 0; j < 16; ++j) S[j] = 0.f;
  const int dv = t >> 2, d0 = (t & 3) * 16;
  for (int c = 0; c < 32; ++c){
    const size_t base = ((size_t)(bh*32 + c))*4096;
    union { unsigned short s[8]; uint4 u; } p0, p1;
    #pragma unroll
    for (int j = 0; j < 8; ++j){ p0.s[j] = f2bf(S[j]); p1.s[j] = f2bf(S[8+j]); }
    *(uint4*)(statesT + base + t*16)     = p0.u;
    *(uint4*)(statesT + base + t*16 + 8) = p1.u;
    #pragma unroll
    for (int j = 0; j < 16; ++j)
      S[j] = g64*S[j] + Tbuf[base + (size_t)(d0 + j)*64 + dv];
  }
}

__global__ __launch_bounds__(256, 2) void retention_chunk(
    const unsigned short* __restrict__ qb, const unsigned short* __restrict__ kb,
    const unsigned short* __restrict__ vb, const unsigned short* __restrict__ gb,
    const unsigned short* __restrict__ statesT, unsigned short* __restrict__ og)
{
  __shared__ unsigned short VT[64*72];
  __shared__ unsigned short Pw[64*72];
  const int t = threadIdx.x, w = t >> 6, ln = t & 63, lg = ln >> 4, lc = ln & 15;
  const int blk = blockIdx.x;          // bh*32 + c
  const int bh = blk >> 5, c = blk & 31;
  const int b = bh >> 4, hh = bh & 15;
  const float lg2g = log2f(1.0f - exp2f(-5.0f - (float)hh));
  float gpr[4];
  #pragma unroll
  for (int r = 0; r < 4; ++r) gpr[r] = exp2f(-lg2g * (float)r);   // gamma^{-r}
  const size_t rowbase = (size_t)(b*2048 + c*64);

  #pragma unroll
  for (int ch = 0; ch < 2; ++ch){
    const int chunk = ch*256 + t;
    const int i = chunk >> 3, d0 = (chunk & 7)*8;
    union {uint4 u; unsigned short s[8];} vv;
    vv.u = *(const uint4*)(vb + (rowbase + i)*1024 + hh*64 + d0);
    #pragma unroll
    for (int j = 0; j < 8; ++j) VT[(d0+j)*72 + i] = vv.s[j];
  }

  bf16x8 Qf[2], Kf[4][2];
  #pragma unroll
  for (int ks = 0; ks < 2; ++ks){
    union {uint4 u; bf16x8 f;} cv;
    cv.u = *(const uint4*)(qb + (rowbase + w*16 + lc)*1024 + hh*64 + ks*32 + lg*8);
    Qf[ks] = cv.f;
    #pragma unroll
    for (int mt = 0; mt < 4; ++mt){
      union {uint4 u; bf16x8 f;} kv;
      kv.u = *(const uint4*)(kb + (rowbase + mt*16 + lc)*1024 + hh*64 + ks*32 + lg*8);
      Kf[mt][ks] = kv.f;
    }
  }

  f32x4 st[4] = {};
  #pragma unroll
  for (int ks = 0; ks < 2; ++ks)
    #pragma unroll
    for (int mt = 0; mt < 4; ++mt)
      st[mt] = __builtin_amdgcn_mfma_f32_16x16x32_bf16(Kf[mt][ks], Qf[ks], st[mt], 0, 0, 0);

  __syncthreads();

  #pragma unroll
  for (int mt = 0; mt < 4; ++mt){
    const int kp = mt*16 + lg*4;
    const int qrow = w*16 + lc;
    const int delta0 = qrow - kp;
    const float dec0 = exp2f(lg2g * (float)delta0) * 0.125f;
    float vals[4];
    #pragma unroll
    for (int r = 0; r < 4; ++r)
      vals[r] = (delta0 >= r) ? st[mt][r] * dec0 * gpr[r] : 0.0f;
    uint2 pk; pk.x = packbf2(vals[0], vals[1]); pk.y = packbf2(vals[2], vals[3]);
    *(uint2*)&Pw[qrow*72 + kp] = pk;
  }

  f32x4 acc[4] = {};
  const unsigned short* Sbase = statesT + (size_t)blk*4096;
  #pragma unroll
  for (int ks = 0; ks < 2; ++ks)
    #pragma unroll
    for (int n = 0; n < 4; ++n){
      union {uint4 u; bf16x8 f;} sv;
      sv.u = *(const uint4*)(Sbase + (n*16 + lc)*64 + ks*32 + lg*8);
      acc[n] = __builtin_amdgcn_mfma_f32_16x16x32_bf16(Qf[ks], sv.f, acc[n], 0, 0, 0);
    }
  #pragma unroll
  for (int n = 0; n < 4; ++n)
    #pragma unroll
    for (int r = 0; r < 4; ++r)
      acc[n][r] *= exp2f(lg2g * (float)(w*16 + lg*4 + r)) * 0.125f;

  #pragma unroll
  for (int ks = 0; ks < 2; ++ks){
    const bf16x8 Pf = *(const bf16x8*)&Pw[(w*16 + lc)*72 + ks*32 + lg*8];
    #pragma unroll
    for (int n = 0; n < 4; ++n){
      const bf16x8 Vf = *(const bf16x8*)&VT[(n*16 + lc)*72 + ks*32 + lg*8];
      acc[n] = __builtin_amdgcn_mfma_f32_16x16x32_bf16(Pf, Vf, acc[n], 0, 0, 0);
    }
  }

  #pragma unroll
  for (int n = 0; n < 4; ++n){
    #pragma unroll
    for (int r = 0; r < 4; ++r){
      const size_t row = rowbase + w*16 + lg*4 + r;
      const int col = hh*64 + n*16 + lc;
      const float gv = bf2f(gb[row*1024 + col]);
      og[row*1024 + col] = f2bf(acc[n][r] * gv);
    }
  }
}

// ================= RVQ: argmin-from-partials + residual/total update =================
__global__ void rvq_update2(const float* __restrict__ cb_l, const float2* __restrict__ partials,
                            float* __restrict__ res, unsigned short* __restrict__ resb,
                            float* __restrict__ total, float* __restrict__ qlpart, int lvl)
{
  const int m = blockIdx.x, t = threadIdx.x;
  __shared__ int sid;
  if (t == 0){
    float best = 3.4e38f; int bi = 0;
    #pragma unroll
    for (int p = 0; p < 16; ++p){
      const float2 pr = partials[m*16 + p];
      if (pr.x < best){ best = pr.x; bi = (int)pr.y; }
    }
    sid = bi;
  }
  __syncthreads();
  const int id = sid;
  const float4 qv = ((const float4*)(cb_l + (size_t)id*1024))[t];
  const float4 rv = ((const float4*)(res + (size_t)m*1024))[t];
  float4 nr; nr.x = rv.x - qv.x; nr.y = rv.y - qv.y; nr.z = rv.z - qv.z; nr.w = rv.w - qv.w;
  float4 tv;
  if (lvl == 0){ tv = qv; }
  else { tv = ((const float4*)(total + (size_t)m*1024))[t];
         tv.x += qv.x; tv.y += qv.y; tv.z += qv.z; tv.w += qv.w; }
  ((float4*)(total + (size_t)m*1024))[t] = tv;
  ((float4*)(res   + (size_t)m*1024))[t] = nr;
  ushort4 nb; nb.x = f2bf(nr.x); nb.y = f2bf(nr.y); nb.z = f2bf(nr.z); nb.w = f2bf(nr.w);
  ((ushort4*)(resb + (size_t)m*1024))[t] = nb;
  float s = nr.x*nr.x + nr.y*nr.y + nr.z*nr.z + nr.w*nr.w;
  #pragma unroll
  for (int o = 32; o >= 1; o >>= 1) s += __shfl_down(s, o);
  __shared__ float red[4];
  if ((t & 63) == 0) red[t >> 6] = s;
  __syncthreads();
  if (t == 0) qlpart[lvl*4096 + m] = red[0]+red[1]+red[2]+red[3];
}

// ================= finals =================
__global__ void final_add(const float* __restrict__ x2, const float* __restrict__ total,
                          float* __restrict__ out)
{
  int i = blockIdx.x*256 + threadIdx.x;
  const float4* a = (const float4*)x2;
  const float4* b = (const float4*)total;
  float4* o = (float4*)out;
  for (; i < 4194304/4; i += gridDim.x*256){
    float4 va = a[i], vb = b[i];
    va.x += vb.x; va.y += vb.y; va.z += vb.z; va.w += vb.w;
    o[i] = va;
  }
}

__global__ void ql_final(const float* __restrict__ qlpart, float* __restrict__ outs)
{
  const int t = threadIdx.x;
  float s = 0.f;
  for (int i = t; i < 16384; i += 256) s += qlpart[i];
  #pragma unroll
  for (int o = 32; o >= 1; o >>= 1) s += __shfl_down(s, o);
  __shared__ float red[4];
  if ((t & 63) == 0) red[t >> 6] = s;
  __syncthreads();
  if (t == 0){
    const float q = (red[0]+red[1]+red[2]+red[3]) * (1.0f/4194304.0f) * 0.25f;
    outs[0] = q; outs[1] = q;
  }
}

// ================= launcher =================
extern "C" void kernel_launch(void* const* d_in, const int* in_sizes, int n_in,
                              void* d_out, int out_size, void* d_ws, size_t ws_size,
                              hipStream_t stream)
{
  const float* x     = (const float*)d_in[0];
  const float* ln1_g = (const float*)d_in[1];
  const float* ln1_b = (const float*)d_in[2];
  const float* wq    = (const float*)d_in[3];
  const float* wk    = (const float*)d_in[4];
  const float* wv    = (const float*)d_in[5];
  const float* wg    = (const float*)d_in[6];
  const float* wo    = (const float*)d_in[7];
  const float* ln2_g = (const float*)d_in[8];
  const float* ln2_b = (const float*)d_in[9];
  const float* w1    = (const float*)d_in[10];
  const float* b1    = (const float*)d_in[11];
  const float* w2    = (const float*)d_in[12];
  const float* b2    = (const float*)d_in[13];
  const float* ln3_g = (const float*)d_in[14];
  const float* ln3_b = (const float*)d_in[15];
  const float* cb    = (const float*)d_in[16];

  char* ws = (char*)d_ws;
  const size_t MB = 1024*1024;
  unsigned short* wqkvgT = (unsigned short*)(ws + 0*MB);   // wq,wk,wv,wg,wo transposed, contiguous
  unsigned short* woT  = (unsigned short*)(ws + 8*MB);
  unsigned short* w1T  = (unsigned short*)(ws + 10*MB);
  unsigned short* w2T  = (unsigned short*)(ws + 18*MB);
  unsigned short* cbbf = (unsigned short*)(ws + 26*MB);
  float* cbn2     = (float*)(ws + 34*MB);                  // 16KB
  float* qlpart   = (float*)(ws + 34*MB + 16*1024);        // 64KB
  float2* partials= (float2*)(ws + 34*MB + 128*1024);      // 512KB
  unsigned short* hbf  = (unsigned short*)(ws + 35*MB);
  unsigned short* qbuf = (unsigned short*)(ws + 43*MB);
  unsigned short* kbuf = (unsigned short*)(ws + 51*MB);
  unsigned short* vbuf = (unsigned short*)(ws + 59*MB);
  unsigned short* gbuf = (unsigned short*)(ws + 67*MB);
  float* skbuf  = (float*)(ws + 43*MB);                    // split-K partials (reuses q/k/v/g, dead by w2)
  unsigned short* ogb  = (unsigned short*)(ws + 75*MB);
  float* x1     = (float*)(ws + 83*MB);
  unsigned short* h2   = (unsigned short*)(ws + 99*MB);
  unsigned short* a1   = (unsigned short*)(ws + 107*MB);
  float* x2     = (float*)(ws + 139*MB);
  float* Tbuf   = (float*)(ws + 139*MB);                   // reuses x2 slot (dead by MLP time)
  float* resf   = (float*)(ws + 155*MB);
  unsigned short* statesT = (unsigned short*)(ws + 155*MB);// reuses resf slot (dead by ln3 time)
  unsigned short* resb = (unsigned short*)(ws + 171*MB);
  float* totalb = (float*)(ws + 187*MB);

  float* outf = (float*)d_out;

  // --- weight prep ---
  Ptr5 p5; p5.p[0]=wq; p5.p[1]=wk; p5.p[2]=wv; p5.p[3]=wg; p5.p[4]=wo;
  hipLaunchKernelGGL(transpose_cvt5, dim3(32,32,5), dim3(256), 0, stream, p5, wqkvgT);
  hipLaunchKernelGGL(transpose_cvt, dim3(128,32), dim3(256), 0, stream, w1, w1T, 1024, 4096);
  hipLaunchKernelGGL(transpose_cvt, dim3(32,128), dim3(256), 0, stream, w2, w2T, 4096, 1024);
  hipLaunchKernelGGL(cvt_bf16x4,    dim3(4096),   dim3(256), 0, stream, cb, cbbf);
  hipLaunchKernelGGL(cbn2_kernel,   dim3(1024),   dim3(256), 0, stream, cb, cbn2);

  // --- retention sub-block ---
  hipLaunchKernelGGL(ln_kernel, dim3(4096), dim3(256), 0, stream, x, ln1_g, ln1_b, hbf, (float*)nullptr);
  hipLaunchKernelGGL((gemm_bt<3,false,false,true>), dim3(32,32), dim3(256), 0, stream,
                     hbf, wqkvgT, (void*)qbuf, (const float*)nullptr, (const float*)nullptr, 4096, 4096, 1024);
  hipLaunchKernelGGL(rope_kernel, dim3(8192), dim3(256), 0, stream, qbuf, kbuf);
  hipLaunchKernelGGL(chunk_sum,  dim3(1024), dim3(256), 0, stream, kbuf, vbuf, Tbuf);
  hipLaunchKernelGGL(chunk_scan, dim3(32),   dim3(256), 0, stream, Tbuf, statesT);
  hipLaunchKernelGGL(retention_chunk, dim3(1024), dim3(256), 0, stream,
                     qbuf, kbuf, vbuf, gbuf, statesT, ogb);
  hipLaunchKernelGGL((gemm64_bt<0,false,true,false,1>), dim3(8,64), dim3(256), 0, stream,
                     ogb, wqkvgT + 4194304, (void*)x1, (const float*)nullptr, x, 4096, 1024, 1024);

  // --- MLP sub-block ---
  hipLaunchKernelGGL(ln_kernel, dim3(4096), dim3(256), 0, stream, x1, ln2_g, ln2_b, h2, (float*)nullptr);
  hipLaunchKernelGGL((gemm_bt<2,true,false,true>), dim3(32,32), dim3(256), 0, stream,
                     h2, w1T, (void*)a1, b1, (const float*)nullptr, 4096, 4096, 1024);
  hipLaunchKernelGGL((gemm64_bt<0,false,false,false,2>), dim3(8,64,2), dim3(256), 0, stream,
                     a1, w2T, (void*)skbuf, (const float*)nullptr, (const float*)nullptr, 4096, 1024, 4096);
  hipLaunchKernelGGL(splitk_reduce, dim3(4096), dim3(256), 0, stream, skbuf, b2, x1, x2);

  // --- RVQ ---
  hipLaunchKernelGGL(ln_kernel, dim3(4096), dim3(256), 0, stream, x2, ln3_g, ln3_b, resb, resf);
  for (int lvl = 0; lvl < 4; ++lvl){
    hipLaunchKernelGGL((gemm64_bt<4,false,false,false,1>), dim3(8,64), dim3(256), 0, stream,
                       resb, cbbf + (size_t)lvl*1048576, (void*)partials,
                       cbn2 + lvl*1024, (const float*)nullptr, 4096, 1024, 1024);
    hipLaunchKernelGGL(rvq_update2, dim3(4096), dim3(256), 0, stream,
                       cb + (size_t)lvl*1048576, partials, resf, resb,
                       totalb, qlpart, lvl);
  }

  // --- outputs ---
  hipLaunchKernelGGL(final_add, dim3(2048), dim3(256), 0, stream, x2, totalb, outf);
  hipLaunchKernelGGL(ql_final, dim3(1), dim3(256), 0, stream, qlpart, outf + 4194304);
}

// Round 5
// 433.008 us; speedup vs baseline: 1.4214x; 1.0246x over previous
//
#include <hip/hip_runtime.h>
#include <cstdint>
#include <cstddef>

#define DEV __device__ __forceinline__

typedef __attribute__((ext_vector_type(8))) short bf16x8;
typedef __attribute__((ext_vector_type(4))) float f32x4;

typedef const __attribute__((address_space(1))) void gl_void;
typedef __attribute__((address_space(3))) void lds_void;

// ---------- small helpers ----------
DEV unsigned short f2bf(float f){
  union { float f; uint32_t u; } v; v.f = f;
  uint32_t r = v.u + 0x7FFFu + ((v.u >> 16) & 1u);  // RNE
  return (unsigned short)(r >> 16);
}
DEV float bf2f(unsigned short u){
  union { uint32_t u; float f; } v; v.u = ((uint32_t)u) << 16; return v.f;
}
DEV uint32_t packbf2(float a, float b){
  return (uint32_t)f2bf(a) | ((uint32_t)f2bf(b) << 16);
}

// ================= LayerNorm (fp32 in -> bf16 out, optional fp32 out) =================
__global__ void ln_kernel(const float* __restrict__ x, const float* __restrict__ gw,
                          const float* __restrict__ bw, unsigned short* __restrict__ obf,
                          float* __restrict__ of32)
{
  const int row = blockIdx.x, t = threadIdx.x;
  const float4 v = ((const float4*)(x + (size_t)row*1024))[t];
  float s  = v.x + v.y + v.z + v.w;
  float s2 = v.x*v.x + v.y*v.y + v.z*v.z + v.w*v.w;
  #pragma unroll
  for (int o = 32; o >= 1; o >>= 1){ s += __shfl_down(s, o); s2 += __shfl_down(s2, o); }
  __shared__ float red[8];
  const int w = t >> 6, ln = t & 63;
  if (ln == 0){ red[w] = s; red[4+w] = s2; }
  __syncthreads();
  const float fs  = red[0]+red[1]+red[2]+red[3];
  const float fs2 = red[4]+red[5]+red[6]+red[7];
  const float mean = fs * (1.0f/1024.0f);
  const float var  = fs2 * (1.0f/1024.0f) - mean*mean;
  const float rstd = rsqrtf(var + 1e-5f);
  const float4 gv = ((const float4*)gw)[t];
  const float4 bv = ((const float4*)bw)[t];
  float4 o4;
  o4.x = (v.x-mean)*rstd*gv.x + bv.x;
  o4.y = (v.y-mean)*rstd*gv.y + bv.y;
  o4.z = (v.z-mean)*rstd*gv.z + bv.z;
  o4.w = (v.w-mean)*rstd*gv.w + bv.w;
  if (of32) ((float4*)(of32 + (size_t)row*1024))[t] = o4;
  ushort4 ob; ob.x = f2bf(o4.x); ob.y = f2bf(o4.y); ob.z = f2bf(o4.z); ob.w = f2bf(o4.w);
  ((ushort4*)(obf + (size_t)row*1024))[t] = ob;
}

// ================= batched transpose + fp32->bf16 (5x 1024x1024), out contiguous ==========
struct Ptr5 { const float* p[5]; };
__global__ void transpose_cvt5(Ptr5 in, unsigned short* __restrict__ out)
{
  __shared__ float tile[32][33];
  const float* src = in.p[blockIdx.z];
  unsigned short* dst = out + (size_t)blockIdx.z*1048576;
  const int c0 = blockIdx.x*32, r0 = blockIdx.y*32;
  const int tx = threadIdx.x & 31, ty = threadIdx.x >> 5;   // 32 x 8
  #pragma unroll
  for (int i = 0; i < 32; i += 8)
    tile[ty+i][tx] = src[(size_t)(r0+ty+i)*1024 + c0 + tx];
  __syncthreads();
  #pragma unroll
  for (int i = 0; i < 32; i += 8)
    dst[(size_t)(c0+ty+i)*1024 + r0 + tx] = f2bf(tile[tx][ty+i]);
}

// ================= transpose + fp32->bf16  (out[C][R] = in[R][C]) =================
__global__ void transpose_cvt(const float* __restrict__ in, unsigned short* __restrict__ out,
                              int R, int C)
{
  __shared__ float tile[32][33];
  const int c0 = blockIdx.x*32, r0 = blockIdx.y*32;
  const int tx = threadIdx.x & 31, ty = threadIdx.x >> 5;   // 32 x 8
  #pragma unroll
  for (int i = 0; i < 32; i += 8)
    tile[ty+i][tx] = in[(size_t)(r0+ty+i)*C + c0 + tx];
  __syncthreads();
  #pragma unroll
  for (int i = 0; i < 32; i += 8)
    out[(size_t)(c0+ty+i)*R + r0 + tx] = f2bf(tile[tx][ty+i]);
}

// ====== fused: codebook fp32 -> bf16 cast + per-code squared norm (one read) ======
__global__ void cvtnorm_kernel(const float* __restrict__ cb, unsigned short* __restrict__ cbbf,
                               float* __restrict__ cbn2)
{
  const int code = blockIdx.x, t = threadIdx.x;     // 4096 codes, 256 thr (1024 elems)
  const float4 v = ((const float4*)(cb + (size_t)code*1024))[t];
  ushort4 o; o.x = f2bf(v.x); o.y = f2bf(v.y); o.z = f2bf(v.z); o.w = f2bf(v.w);
  ((ushort4*)(cbbf + (size_t)code*1024))[t] = o;
  float s = v.x*v.x + v.y*v.y + v.z*v.z + v.w*v.w;
  #pragma unroll
  for (int off = 32; off >= 1; off >>= 1) s += __shfl_down(s, off);
  __shared__ float red[4];
  if ((t & 63) == 0) red[t >> 6] = s;
  __syncthreads();
  if (t == 0) cbn2[code] = red[0]+red[1]+red[2]+red[3];
}

// ================= GEMM 128x128, BK=32 (m97 structure), 4+ blocks/CU =================
// EPI: 0 none, 1 silu, 2 gelu(exact), 3 QKVG-split (rope on sects 0,1; silu on sect 3).
template<int EPI, bool BIAS, bool RES, bool OUTBF>
__global__ __launch_bounds__(256, 4) void gemm_bt(
    const unsigned short* __restrict__ A, const unsigned short* __restrict__ BT,
    void* __restrict__ Cv, const float* __restrict__ bias, const float* __restrict__ resid,
    int M, int N, int K)
{
  __shared__ __align__(16) unsigned short As[2][128*32];
  __shared__ __align__(16) unsigned short Bs[2][128*32];
  const int t = threadIdx.x;
  const int w = t >> 6, ln = t & 63, lg = ln >> 4, lc = ln & 15;
  // chunked XCD swizzle (bijective; nwg % 8 == 0)
  const int gx = gridDim.x, nwg = gridDim.x * gridDim.y;
  int lin = blockIdx.y * gx + blockIdx.x;
  lin = (lin >> 3) + (lin & 7) * (nwg >> 3);
  const int m0 = (lin / gx) * 128, n0 = (lin % gx) * 128;
  const int wr = (w >> 1) * 64, wc = (w & 1) * 64;
  f32x4 acc[4][4] = {};
  const int nkt = K >> 5;

  auto stage = [&](int buf, int kt){
    #pragma unroll
    for (int c = 0; c < 2; ++c){
      const int chunk = c*256 + t;
      const int row = chunk >> 2, ke = (chunk & 3) * 8;
      __builtin_amdgcn_global_load_lds(
          (gl_void*)(A + (size_t)(m0+row)*K + (size_t)kt*32 + ke),
          (lds_void*)&As[buf][(c*256 + w*64)*8], 16, 0, 0);
      __builtin_amdgcn_global_load_lds(
          (gl_void*)(BT + (size_t)(n0+row)*K + (size_t)kt*32 + ke),
          (lds_void*)&Bs[buf][(c*256 + w*64)*8], 16, 0, 0);
    }
  };

  stage(0, 0);
  __syncthreads();
  for (int kt = 0; kt < nkt; ++kt){
    const int cur = kt & 1;
    if (kt + 1 < nkt) stage(cur ^ 1, kt + 1);
    bf16x8 af[4], bfr[4];
    #pragma unroll
    for (int i = 0; i < 4; ++i){
      af[i]  = *(const bf16x8*)&As[cur][(wr + i*16 + lc)*32 + lg*8];
      bfr[i] = *(const bf16x8*)&Bs[cur][(wc + i*16 + lc)*32 + lg*8];
    }
    #pragma unroll
    for (int m = 0; m < 4; ++m)
      #pragma unroll
      for (int n = 0; n < 4; ++n)
        acc[m][n] = __builtin_amdgcn_mfma_f32_16x16x32_bf16(af[m], bfr[n], acc[m][n], 0, 0, 0);
    __syncthreads();
  }

  if constexpr (EPI == 3){
    // sect is wave-uniform (wave spans 64 cols inside a 1024-col section)
    const int sect = (n0 + wc) >> 10;
    unsigned short* outp = (unsigned short*)Cv + (size_t)sect*4194304;
    #pragma unroll
    for (int m = 0; m < 4; ++m){
      #pragma unroll
      for (int r = 0; r < 4; ++r){
        const int row = m0 + wr + m*16 + lg*4 + r;
        const int s_ = row & 2047;
        #pragma unroll
        for (int n = 0; n < 4; ++n){
          const int col = n0 + wc + n*16 + lc;
          const int c1 = col & 1023;
          float v = acc[m][n][r];
          if (sect <= 1){               // rope on q,k
            const int j = c1 & 31;
            const float ang = (float)s_ * exp2f(-(float)j * 0.4152410118609203f);
            float sn, cs; sincosf(ang, &sn, &cs);
            const float vp = acc[m][n ^ 2][r];   // partner col ^ 32
            v = (c1 & 32) ? (v*cs + vp*sn) : (v*cs - vp*sn);
          } else if (sect == 3){        // silu gate
            v = v * (1.0f / (1.0f + __expf(-v)));
          }
          outp[(size_t)row*1024 + c1] = f2bf(v);
        }
      }
    }
    return;
  }

  #pragma unroll
  for (int m = 0; m < 4; ++m){
    #pragma unroll
    for (int n = 0; n < 4; ++n){
      #pragma unroll
      for (int r = 0; r < 4; ++r){
        const int row = m0 + wr + m*16 + lg*4 + r;
        const int col = n0 + wc + n*16 + lc;
        float v = acc[m][n][r];
        if constexpr (BIAS) v += bias[col];
        if constexpr (EPI == 1) v = v * (1.0f / (1.0f + __expf(-v)));
        if constexpr (EPI == 2) v = 0.5f * v * (1.0f + erff(v * 0.70710678118654752f));
        if constexpr (RES) v += resid[(size_t)row*N + col];
        if constexpr (OUTBF) ((unsigned short*)Cv)[(size_t)row*N + col] = f2bf(v);
        else                 ((float*)Cv)[(size_t)row*N + col] = v;
      }
    }
  }
}

// ================= GEMM 64x128, BK=64, swizzled; optional split-K =================
// EPI: 0 none, 4 argmin-partials (bias = cbn2).
template<int EPI, bool BIAS, bool RES, bool OUTBF, int NSPLIT>
__global__ __launch_bounds__(256, 3) void gemm64_bt(
    const unsigned short* __restrict__ A, const unsigned short* __restrict__ BT,
    void* __restrict__ Cv, const float* __restrict__ bias, const float* __restrict__ resid,
    int M, int N, int K)
{
  __shared__ __align__(16) unsigned short As[2][64*64];
  __shared__ __align__(16) unsigned short Bs[2][128*64];
  const int t = threadIdx.x;
  const int w = t >> 6, ln = t & 63, lg = ln >> 4, lc = ln & 15;
  const int gx = gridDim.x, nwg = gridDim.x * gridDim.y;
  int lin = blockIdx.y * gx + blockIdx.x;
  lin = (lin >> 3) + (lin & 7) * (nwg >> 3);
  const int bx = lin % gx, by = lin / gx;
  const int m0 = by * 64, n0 = bx * 128;
  const int wr = (w >> 1) * 32, wc = (w & 1) * 64;
  f32x4 acc[2][4] = {};
  const int nkt = (K >> 6) / NSPLIT;
  const int ktb = (NSPLIT > 1) ? blockIdx.z * nkt : 0;

  auto stage = [&](int buf, int kt){
    #pragma unroll
    for (int c = 0; c < 2; ++c){
      const int chunk = c*256 + t;
      const int row = chunk >> 3;
      const int kb = (((chunk & 7) << 4) ^ ((row & 7) << 4)) >> 1;
      __builtin_amdgcn_global_load_lds(
          (gl_void*)(A + (size_t)(m0+row)*K + (size_t)(ktb+kt)*64 + kb),
          (lds_void*)&As[buf][(c*256 + w*64)*8], 16, 0, 0);
    }
    #pragma unroll
    for (int c = 0; c < 4; ++c){
      const int chunk = c*256 + t;
      const int row = chunk >> 3;
      const int kb = (((chunk & 7) << 4) ^ ((row & 7) << 4)) >> 1;
      __builtin_amdgcn_global_load_lds(
          (gl_void*)(BT + (size_t)(n0+row)*K + (size_t)(ktb+kt)*64 + kb),
          (lds_void*)&Bs[buf][(c*256 + w*64)*8], 16, 0, 0);
    }
  };

  stage(0, 0);
  __syncthreads();
  for (int kt = 0; kt < nkt; ++kt){
    const int cur = kt & 1;
    if (kt + 1 < nkt) stage(cur ^ 1, kt + 1);
    #pragma unroll
    for (int ks = 0; ks < 2; ++ks){
      bf16x8 af[2], bfr[4];
      #pragma unroll
      for (int i = 0; i < 2; ++i){
        const int rowA = wr + i*16 + lc;
        const int colA = (((ks<<6) + (lg<<4)) ^ ((rowA & 7) << 4)) >> 1;
        af[i] = *(const bf16x8*)&As[cur][rowA*64 + colA];
      }
      #pragma unroll
      for (int i = 0; i < 4; ++i){
        const int rowB = wc + i*16 + lc;
        const int colB = (((ks<<6) + (lg<<4)) ^ ((rowB & 7) << 4)) >> 1;
        bfr[i] = *(const bf16x8*)&Bs[cur][rowB*64 + colB];
      }
      #pragma unroll
      for (int m = 0; m < 2; ++m)
        #pragma unroll
        for (int n = 0; n < 4; ++n)
          acc[m][n] = __builtin_amdgcn_mfma_f32_16x16x32_bf16(af[m], bfr[n], acc[m][n], 0, 0, 0);
    }
    __syncthreads();
  }

  if constexpr (EPI == 4){
    #pragma unroll
    for (int m = 0; m < 2; ++m){
      #pragma unroll
      for (int r = 0; r < 4; ++r){
        float best = 3.4e38f; int bi = 0;
        #pragma unroll
        for (int n = 0; n < 4; ++n){
          const int col = n0 + wc + n*16 + lc;
          const float d = bias[col] - 2.0f*acc[m][n][r];
          if (d < best){ best = d; bi = col; }
        }
        #pragma unroll
        for (int o = 1; o < 16; o <<= 1){
          const float ob = __shfl_xor(best, o);
          const int oi = __shfl_xor(bi, o);
          if (ob < best || (ob == best && oi < bi)){ best = ob; bi = oi; }
        }
        if (lc == 0){
          const int row = m0 + wr + m*16 + lg*4 + r;
          ((float2*)Cv)[row*16 + bx*2 + (w & 1)] = make_float2(best, (float)bi);
        }
      }
    }
    return;
  }

  float* Cp = (float*)Cv + (NSPLIT > 1 ? (size_t)blockIdx.z * (size_t)M * N : 0);
  #pragma unroll
  for (int m = 0; m < 2; ++m){
    #pragma unroll
    for (int n = 0; n < 4; ++n){
      #pragma unroll
      for (int r = 0; r < 4; ++r){
        const int row = m0 + wr + m*16 + lg*4 + r;
        const int col = n0 + wc + n*16 + lc;
        float v = acc[m][n][r];
        if constexpr (BIAS) v += bias[col];
        if constexpr (RES) v += resid[(size_t)row*N + col];
        if constexpr (OUTBF) ((unsigned short*)Cv)[(size_t)row*N + col] = f2bf(v);
        else                 Cp[(size_t)row*N + col] = v;
      }
    }
  }
}

// ================= split-K reduce: out = p0 + p1 + bias + resid =================
__global__ void splitk_reduce(const float* __restrict__ p, const float* __restrict__ bias,
                              const float* __restrict__ resid, float* __restrict__ out)
{
  const int i = blockIdx.x*256 + threadIdx.x;   // float4 index over 4096*1024/4
  const float4 a = ((const float4*)p)[i];
  const float4 b = ((const float4*)(p + 4194304))[i];
  const float4 rv = ((const float4*)resid)[i];
  const float4 bv = ((const float4*)bias)[i & 255];
  float4 o;
  o.x = a.x + b.x + rv.x + bv.x;
  o.y = a.y + b.y + rv.y + bv.y;
  o.z = a.z + b.z + rv.z + bv.z;
  o.w = a.w + b.w + rv.w + bv.w;
  ((float4*)out)[i] = o;
}

// ================= Chunkwise retention, C=64 =================
__global__ __launch_bounds__(256, 2) void chunk_sum(
    const unsigned short* __restrict__ kb, const unsigned short* __restrict__ vb,
    float* __restrict__ Tbuf)
{
  __shared__ unsigned short KT[64*72];
  __shared__ unsigned short VT[64*72];
  const int t = threadIdx.x, w = t >> 6, ln = t & 63, lg = ln >> 4, lc = ln & 15;
  const int blk = blockIdx.x;          // bh*32 + c
  const int bh = blk >> 5, c = blk & 31;
  const int b = bh >> 4, hh = bh & 15;
  const float lg2g = log2f(1.0f - exp2f(-5.0f - (float)hh));
  #pragma unroll
  for (int ch = 0; ch < 2; ++ch){
    const int chunk = ch*256 + t;
    const int i = chunk >> 3, d0 = (chunk & 7)*8;
    const size_t gofs = ((size_t)(b*2048 + c*64 + i))*1024 + hh*64 + d0;
    const float wi = exp2f(lg2g * (float)(64 - i));
    union {uint4 u; unsigned short s[8];} kv, vv;
    kv.u = *(const uint4*)(kb + gofs);
    vv.u = *(const uint4*)(vb + gofs);
    #pragma unroll
    for (int j = 0; j < 8; ++j){
      KT[(d0+j)*72 + i] = f2bf(bf2f(kv.s[j]) * wi);
      VT[(d0+j)*72 + i] = vv.s[j];
    }
  }
  __syncthreads();
  f32x4 acc[4] = {};
  #pragma unroll
  for (int ks = 0; ks < 2; ++ks){
    const bf16x8 af = *(const bf16x8*)&KT[(w*16 + lc)*72 + ks*32 + lg*8];
    #pragma unroll
    for (int n = 0; n < 4; ++n){
      const bf16x8 bf = *(const bf16x8*)&VT[(n*16 + lc)*72 + ks*32 + lg*8];
      acc[n] = __builtin_amdgcn_mfma_f32_16x16x32_bf16(af, bf, acc[n], 0, 0, 0);
    }
  }
  float* out = Tbuf + (size_t)blk*4096;
  #pragma unroll
  for (int n = 0; n < 4; ++n)
    #pragma unroll
    for (int r = 0; r < 4; ++r)
      out[(w*16 + lg*4 + r)*64 + n*16 + lc] = acc[n][r];
}

__global__ void chunk_scan(const float* __restrict__ Tbuf, unsigned short* __restrict__ statesT)
{
  const int bh = blockIdx.x, t = threadIdx.x;
  const int hh = bh & 15;
  const float gamma = 1.0f - exp2f(-5.0f - (float)hh);
  const float g64 = exp2f(log2f(gamma) * 64.0f);
  float S[16];
  #pragma unroll
  for (int j = 0; j < 16; ++j) S[j] = 0.f;
  const int dv = t >> 2, d0 = (t & 3) * 16;
  for (int c = 0; c < 32; ++c){
    const size_t base = ((size_t)(bh*32 + c))*4096;
    union { unsigned short s[8]; uint4 u; } p0, p1;
    #pragma unroll
    for (int j = 0; j < 8; ++j){ p0.s[j] = f2bf(S[j]); p1.s[j] = f2bf(S[8+j]); }
    *(uint4*)(statesT + base + t*16)     = p0.u;
    *(uint4*)(statesT + base + t*16 + 8) = p1.u;
    #pragma unroll
    for (int j = 0; j < 16; ++j)
      S[j] = g64*S[j] + Tbuf[base + (size_t)(d0 + j)*64 + dv];
  }
}

__global__ __launch_bounds__(256, 2) void retention_chunk(
    const unsigned short* __restrict__ qb, const unsigned short* __restrict__ kb,
    const unsigned short* __restrict__ vb, const unsigned short* __restrict__ gb,
    const unsigned short* __restrict__ statesT, unsigned short* __restrict__ og)
{
  __shared__ unsigned short VT[64*72];
  __shared__ unsigned short Pw[64*72];
  const int t = threadIdx.x, w = t >> 6, ln = t & 63, lg = ln >> 4, lc = ln & 15;
  const int blk = blockIdx.x;          // bh*32 + c
  const int bh = blk >> 5, c = blk & 31;
  const int b = bh >> 4, hh = bh & 15;
  const float lg2g = log2f(1.0f - exp2f(-5.0f - (float)hh));
  float gpr[4];
  #pragma unroll
  for (int r = 0; r < 4; ++r) gpr[r] = exp2f(-lg2g * (float)r);   // gamma^{-r}
  const size_t rowbase = (size_t)(b*2048 + c*64);

  #pragma unroll
  for (int ch = 0; ch < 2; ++ch){
    const int chunk = ch*256 + t;
    const int i = chunk >> 3, d0 = (chunk & 7)*8;
    union {uint4 u; unsigned short s[8];} vv;
    vv.u = *(const uint4*)(vb + (rowbase + i)*1024 + hh*64 + d0);
    #pragma unroll
    for (int j = 0; j < 8; ++j) VT[(d0+j)*72 + i] = vv.s[j];
  }

  bf16x8 Qf[2], Kf[4][2];
  #pragma unroll
  for (int ks = 0; ks < 2; ++ks){
    union {uint4 u; bf16x8 f;} cv;
    cv.u = *(const uint4*)(qb + (rowbase + w*16 + lc)*1024 + hh*64 + ks*32 + lg*8);
    Qf[ks] = cv.f;
    #pragma unroll
    for (int mt = 0; mt < 4; ++mt){
      union {uint4 u; bf16x8 f;} kv;
      kv.u = *(const uint4*)(kb + (rowbase + mt*16 + lc)*1024 + hh*64 + ks*32 + lg*8);
      Kf[mt][ks] = kv.f;
    }
  }

  f32x4 st[4] = {};
  #pragma unroll
  for (int ks = 0; ks < 2; ++ks)
    #pragma unroll
    for (int mt = 0; mt < 4; ++mt)
      st[mt] = __builtin_amdgcn_mfma_f32_16x16x32_bf16(Kf[mt][ks], Qf[ks], st[mt], 0, 0, 0);

  __syncthreads();

  #pragma unroll
  for (int mt = 0; mt < 4; ++mt){
    const int kp = mt*16 + lg*4;
    const int qrow = w*16 + lc;
    const int delta0 = qrow - kp;
    const float dec0 = exp2f(lg2g * (float)delta0) * 0.125f;
    float vals[4];
    #pragma unroll
    for (int r = 0; r < 4; ++r)
      vals[r] = (delta0 >= r) ? st[mt][r] * dec0 * gpr[r] : 0.0f;
    uint2 pk; pk.x = packbf2(vals[0], vals[1]); pk.y = packbf2(vals[2], vals[3]);
    *(uint2*)&Pw[qrow*72 + kp] = pk;
  }

  f32x4 acc[4] = {};
  const unsigned short* Sbase = statesT + (size_t)blk*4096;
  #pragma unroll
  for (int ks = 0; ks < 2; ++ks)
    #pragma unroll
    for (int n = 0; n < 4; ++n){
      union {uint4 u; bf16x8 f;} sv;
      sv.u = *(const uint4*)(Sbase + (n*16 + lc)*64 + ks*32 + lg*8);
      acc[n] = __builtin_amdgcn_mfma_f32_16x16x32_bf16(Qf[ks], sv.f, acc[n], 0, 0, 0);
    }
  #pragma unroll
  for (int n = 0; n < 4; ++n)
    #pragma unroll
    for (int r = 0; r < 4; ++r)
      acc[n][r] *= exp2f(lg2g * (float)(w*16 + lg*4 + r)) * 0.125f;

  #pragma unroll
  for (int ks = 0; ks < 2; ++ks){
    const bf16x8 Pf = *(const bf16x8*)&Pw[(w*16 + lc)*72 + ks*32 + lg*8];
    #pragma unroll
    for (int n = 0; n < 4; ++n){
      const bf16x8 Vf = *(const bf16x8*)&VT[(n*16 + lc)*72 + ks*32 + lg*8];
      acc[n] = __builtin_amdgcn_mfma_f32_16x16x32_bf16(Pf, Vf, acc[n], 0, 0, 0);
    }
  }

  #pragma unroll
  for (int n = 0; n < 4; ++n){
    #pragma unroll
    for (int r = 0; r < 4; ++r){
      const size_t row = rowbase + w*16 + lg*4 + r;
      const int col = hh*64 + n*16 + lc;
      const float gv = bf2f(gb[row*1024 + col]);
      og[row*1024 + col] = f2bf(acc[n][r] * gv);
    }
  }
}

// ===== RVQ: argmin-from-partials + residual update (no total buffer) =====
__global__ void rvq_update3(const float* __restrict__ cb_l, const float2* __restrict__ partials,
                            const float* __restrict__ res_in, float* __restrict__ res_out,
                            unsigned short* __restrict__ resb, float* __restrict__ qlpart, int lvl)
{
  const int m = blockIdx.x, t = threadIdx.x;
  __shared__ int sid;
  if (t == 0){
    float best = 3.4e38f; int bi = 0;
    #pragma unroll
    for (int p = 0; p < 16; ++p){
      const float2 pr = partials[m*16 + p];
      if (pr.x < best){ best = pr.x; bi = (int)pr.y; }
    }
    sid = bi;
  }
  __syncthreads();
  const int id = sid;
  const float4 qv = ((const float4*)(cb_l + (size_t)id*1024))[t];
  const float4 rv = ((const float4*)(res_in + (size_t)m*1024))[t];
  float4 nr; nr.x = rv.x - qv.x; nr.y = rv.y - qv.y; nr.z = rv.z - qv.z; nr.w = rv.w - qv.w;
  ((float4*)(res_out + (size_t)m*1024))[t] = nr;
  ushort4 nb; nb.x = f2bf(nr.x); nb.y = f2bf(nr.y); nb.z = f2bf(nr.z); nb.w = f2bf(nr.w);
  ((ushort4*)(resb + (size_t)m*1024))[t] = nb;
  float s = nr.x*nr.x + nr.y*nr.y + nr.z*nr.z + nr.w*nr.w;
  #pragma unroll
  for (int o = 32; o >= 1; o >>= 1) s += __shfl_down(s, o);
  __shared__ float red[4];
  if ((t & 63) == 0) red[t >> 6] = s;
  __syncthreads();
  if (t == 0) qlpart[lvl*4096 + m] = red[0]+red[1]+red[2]+red[3];
}

// ================= finals =================
// out = x2 + xn - res4   (total == xn - final residual)
__global__ void final_add3(const float* __restrict__ x2, const float* __restrict__ xn,
                           const float* __restrict__ res4, float* __restrict__ out)
{
  const int i = blockIdx.x*256 + threadIdx.x;
  const float4 a = ((const float4*)x2)[i];
  const float4 b = ((const float4*)xn)[i];
  const float4 c = ((const float4*)res4)[i];
  float4 o;
  o.x = a.x + b.x - c.x;
  o.y = a.y + b.y - c.y;
  o.z = a.z + b.z - c.z;
  o.w = a.w + b.w - c.w;
  ((float4*)out)[i] = o;
}

__global__ void ql_final(const float* __restrict__ qlpart, float* __restrict__ outs)
{
  const int t = threadIdx.x;
  float s = 0.f;
  for (int i = t; i < 16384; i += 256) s += qlpart[i];
  #pragma unroll
  for (int o = 32; o >= 1; o >>= 1) s += __shfl_down(s, o);
  __shared__ float red[4];
  if ((t & 63) == 0) red[t >> 6] = s;
  __syncthreads();
  if (t == 0){
    const float q = (red[0]+red[1]+red[2]+red[3]) * (1.0f/4194304.0f) * 0.25f;
    outs[0] = q; outs[1] = q;
  }
}

// ================= launcher =================
extern "C" void kernel_launch(void* const* d_in, const int* in_sizes, int n_in,
                              void* d_out, int out_size, void* d_ws, size_t ws_size,
                              hipStream_t stream)
{
  const float* x     = (const float*)d_in[0];
  const float* ln1_g = (const float*)d_in[1];
  const float* ln1_b = (const float*)d_in[2];
  const float* wq    = (const float*)d_in[3];
  const float* wk    = (const float*)d_in[4];
  const float* wv    = (const float*)d_in[5];
  const float* wg    = (const float*)d_in[6];
  const float* wo    = (const float*)d_in[7];
  const float* ln2_g = (const float*)d_in[8];
  const float* ln2_b = (const float*)d_in[9];
  const float* w1    = (const float*)d_in[10];
  const float* b1    = (const float*)d_in[11];
  const float* w2    = (const float*)d_in[12];
  const float* b2    = (const float*)d_in[13];
  const float* ln3_g = (const float*)d_in[14];
  const float* ln3_b = (const float*)d_in[15];
  const float* cb    = (const float*)d_in[16];

  char* ws = (char*)d_ws;
  const size_t MB = 1024*1024;
  unsigned short* wqkvgT = (unsigned short*)(ws + 0*MB);   // wq,wk,wv,wg,wo transposed, contiguous
  unsigned short* w1T  = (unsigned short*)(ws + 10*MB);
  unsigned short* w2T  = (unsigned short*)(ws + 18*MB);
  unsigned short* cbbf = (unsigned short*)(ws + 26*MB);
  float* cbn2     = (float*)(ws + 34*MB);                  // 16KB
  float* qlpart   = (float*)(ws + 34*MB + 16*1024);        // 64KB
  float2* partials= (float2*)(ws + 34*MB + 128*1024);      // 512KB
  unsigned short* hbf  = (unsigned short*)(ws + 35*MB);
  unsigned short* qbuf = (unsigned short*)(ws + 43*MB);
  unsigned short* kbuf = (unsigned short*)(ws + 51*MB);
  unsigned short* vbuf = (unsigned short*)(ws + 59*MB);
  unsigned short* gbuf = (unsigned short*)(ws + 67*MB);
  float* skbuf  = (float*)(ws + 43*MB);                    // split-K partials (reuses q/k/v/g, dead by w2)
  unsigned short* ogb  = (unsigned short*)(ws + 75*MB);
  float* x1     = (float*)(ws + 83*MB);
  unsigned short* h2   = (unsigned short*)(ws + 99*MB);
  unsigned short* a1   = (unsigned short*)(ws + 107*MB);
  float* x2     = (float*)(ws + 139*MB);
  float* Tbuf   = (float*)(ws + 139*MB);                   // reuses x2 slot (dead by MLP time)
  float* xnf    = (float*)(ws + 155*MB);                   // fp32 xn (kept to the end)
  unsigned short* statesT = (unsigned short*)(ws + 155*MB);// reuses xnf slot (dead by ln3 time)
  unsigned short* resb = (unsigned short*)(ws + 171*MB);
  float* resw   = (float*)(ws + 187*MB);                   // fp32 running residual

  float* outf = (float*)d_out;

  // --- weight prep ---
  Ptr5 p5; p5.p[0]=wq; p5.p[1]=wk; p5.p[2]=wv; p5.p[3]=wg; p5.p[4]=wo;
  hipLaunchKernelGGL(transpose_cvt5, dim3(32,32,5), dim3(256), 0, stream, p5, wqkvgT);
  hipLaunchKernelGGL(transpose_cvt, dim3(128,32), dim3(256), 0, stream, w1, w1T, 1024, 4096);
  hipLaunchKernelGGL(transpose_cvt, dim3(32,128), dim3(256), 0, stream, w2, w2T, 4096, 1024);
  hipLaunchKernelGGL(cvtnorm_kernel, dim3(4096), dim3(256), 0, stream, cb, cbbf, cbn2);

  // --- retention sub-block ---
  hipLaunchKernelGGL(ln_kernel, dim3(4096), dim3(256), 0, stream, x, ln1_g, ln1_b, hbf, (float*)nullptr);
  hipLaunchKernelGGL((gemm_bt<3,false,false,true>), dim3(32,32), dim3(256), 0, stream,
                     hbf, wqkvgT, (void*)qbuf, (const float*)nullptr, (const float*)nullptr, 4096, 4096, 1024);
  hipLaunchKernelGGL(chunk_sum,  dim3(1024), dim3(256), 0, stream, kbuf, vbuf, Tbuf);
  hipLaunchKernelGGL(chunk_scan, dim3(32),   dim3(256), 0, stream, Tbuf, statesT);
  hipLaunchKernelGGL(retention_chunk, dim3(1024), dim3(256), 0, stream,
                     qbuf, kbuf, vbuf, gbuf, statesT, ogb);
  hipLaunchKernelGGL((gemm64_bt<0,false,true,false,1>), dim3(8,64), dim3(256), 0, stream,
                     ogb, wqkvgT + 4194304, (void*)x1, (const float*)nullptr, x, 4096, 1024, 1024);

  // --- MLP sub-block ---
  hipLaunchKernelGGL(ln_kernel, dim3(4096), dim3(256), 0, stream, x1, ln2_g, ln2_b, h2, (float*)nullptr);
  hipLaunchKernelGGL((gemm_bt<2,true,false,true>), dim3(32,32), dim3(256), 0, stream,
                     h2, w1T, (void*)a1, b1, (const float*)nullptr, 4096, 4096, 1024);
  hipLaunchKernelGGL((gemm64_bt<0,false,false,false,2>), dim3(8,64,2), dim3(256), 0, stream,
                     a1, w2T, (void*)skbuf, (const float*)nullptr, (const float*)nullptr, 4096, 1024, 4096);
  hipLaunchKernelGGL(splitk_reduce, dim3(4096), dim3(256), 0, stream, skbuf, b2, x1, x2);

  // --- RVQ ---
  hipLaunchKernelGGL(ln_kernel, dim3(4096), dim3(256), 0, stream, x2, ln3_g, ln3_b, resb, xnf);
  for (int lvl = 0; lvl < 4; ++lvl){
    hipLaunchKernelGGL((gemm64_bt<4,false,false,false,1>), dim3(8,64), dim3(256), 0, stream,
                       resb, cbbf + (size_t)lvl*1048576, (void*)partials,
                       cbn2 + lvl*1024, (const float*)nullptr, 4096, 1024, 1024);
    hipLaunchKernelGGL(rvq_update3, dim3(4096), dim3(256), 0, stream,
                       cb + (size_t)lvl*1048576, partials,
                       (lvl == 0) ? xnf : resw, resw, resb, qlpart, lvl);
  }

  // --- outputs ---
  hipLaunchKernelGGL(final_add3, dim3(4096), dim3(256), 0, stream, x2, xnf, resw, outf);
  hipLaunchKernelGGL(ql_final, dim3(1), dim3(256), 0, stream, qlpart, outf + 4194304);
}